// Round 1
// baseline (3386.412 us; speedup 1.0000x reference)
//
#include <hip/hip_runtime.h>
#include <math.h>

#define Bdim 2
#define Nn   2048
#define Kn   30
#define DNc  256
#define DEc  128
#define NODES (Bdim*Nn)      // 4096
#define EDGES (Bdim*Nn*Kn)   // 122880
#define EPSF 1e-6f

__device__ __forceinline__ float softplusf(float x){
    return fmaxf(x, 0.f) + log1pf(expf(-fabsf(x)));
}

// ---------------- K1: per-node geometry: Xc, R, 12-dim feat, mask ----------------
__global__ __launch_bounds__(256) void k_geom(
    const float* __restrict__ X, const int* __restrict__ C,
    float* __restrict__ Xc, float* __restrict__ Rm,
    float* __restrict__ feat, float* __restrict__ mask_out)
{
    int id = blockIdx.x*256 + threadIdx.x;
    if (id >= NODES) return;
    float a[4][3];
    #pragma unroll
    for (int t=0;t<4;++t)
        #pragma unroll
        for (int d=0;d<3;++d) a[t][d] = X[id*12 + t*3 + d];
    // Xc = mean over atoms, exact-order f32 (feeds top-k: no FMA contraction)
    #pragma unroll
    for (int d=0; d<3; ++d){
        float s = __fadd_rn(__fadd_rn(__fadd_rn(a[0][d],a[1][d]),a[2][d]),a[3][d]);
        Xc[id*3+d] = __fmul_rn(s, 0.25f);
    }
    mask_out[id] = (C[id] > 0) ? 1.f : 0.f;

    float u[3], v[3], w[3], b2[3], v0[3], vv[3];
    #pragma unroll
    for (int d=0;d<3;++d) b2[d] = a[2][d]-a[1][d];          // Cat - CA
    float n2 = sqrtf(b2[0]*b2[0]+b2[1]*b2[1]+b2[2]*b2[2]);
    #pragma unroll
    for (int d=0;d<3;++d) u[d] = b2[d]/(n2+EPSF);
    #pragma unroll
    for (int d=0;d<3;++d) v0[d] = a[0][d]-a[1][d];          // Nat - CA
    float dt = v0[0]*u[0]+v0[1]*u[1]+v0[2]*u[2];
    #pragma unroll
    for (int d=0;d<3;++d) vv[d] = v0[d] - dt*u[d];
    float nv = sqrtf(vv[0]*vv[0]+vv[1]*vv[1]+vv[2]*vv[2]);
    #pragma unroll
    for (int d=0;d<3;++d) v[d] = vv[d]/(nv+EPSF);
    w[0] = u[1]*v[2]-u[2]*v[1];
    w[1] = u[2]*v[0]-u[0]*v[2];
    w[2] = u[0]*v[1]-u[1]*v[0];
    #pragma unroll
    for (int d=0;d<3;++d){
        Rm[id*9 + d*3 + 0] = u[d];
        Rm[id*9 + d*3 + 1] = v[d];
        Rm[id*9 + d*3 + 2] = w[d];
    }
    // bond feats: [CA-Nat, Cat-CA, Oat-Cat], each [unit(3), log(|.|+eps)]
    float bonds[3][3];
    #pragma unroll
    for (int d=0;d<3;++d){
        bonds[0][d] = a[1][d]-a[0][d];
        bonds[1][d] = b2[d];
        bonds[2][d] = a[3][d]-a[2][d];
    }
    #pragma unroll
    for (int bi=0;bi<3;++bi){
        float nb = sqrtf(bonds[bi][0]*bonds[bi][0]+bonds[bi][1]*bonds[bi][1]+bonds[bi][2]*bonds[bi][2]);
        #pragma unroll
        for (int d=0;d<3;++d) feat[id*12 + bi*4 + d] = bonds[bi][d]/(nb+EPSF);
        feat[id*12 + bi*4 + 3] = logf(nb+EPSF);
    }
}

// ---------------- K1b: node_h init = (feat @ Wn + bn) * mask ----------------
__global__ __launch_bounds__(256) void k_nodeh(
    const float* __restrict__ feat, const float* __restrict__ Wn,
    const float* __restrict__ bn, const int* __restrict__ C,
    float* __restrict__ node_h)
{
    int nid = blockIdx.x;
    int c   = threadIdx.x;   // 256 = DN
    __shared__ float f[12];
    if (c < 12) f[c] = feat[nid*12 + c];
    __syncthreads();
    float acc = bn[c];
    #pragma unroll
    for (int k=0;k<12;++k) acc += f[k]*Wn[k*DNc + c];
    float mask = (C[nid] > 0) ? 1.f : 0.f;
    node_h[nid*DNc + c] = acc*mask;
}

// ---------------- K2: kNN top-30 per node (exact top_k semantics) ----------------
__global__ __launch_bounds__(256) void k_knn(
    const float* __restrict__ Xc, const int* __restrict__ C,
    int* __restrict__ eidx, float* __restrict__ eidx_f)
{
    __shared__ float d2[Nn];
    __shared__ float rv[256];
    __shared__ int   ri[256];
    int b = blockIdx.x >> 11;
    int i = blockIdx.x & (Nn-1);
    const float* xcb = Xc + (size_t)b*Nn*3;
    const int*   Cb  = C  + (size_t)b*Nn;
    float xi0 = xcb[i*3+0], xi1 = xcb[i*3+1], xi2 = xcb[i*3+2];
    for (int j=threadIdx.x; j<Nn; j+=256){
        float dx = __fsub_rn(xi0, xcb[j*3+0]);
        float dy = __fsub_rn(xi1, xcb[j*3+1]);
        float dz = __fsub_rn(xi2, xcb[j*3+2]);
        float vv = __fadd_rn(__fadd_rn(__fmul_rn(dx,dx),__fmul_rn(dy,dy)),__fmul_rn(dz,dz));
        if (Cb[j] <= 0) vv = __fadd_rn(vv, 1e9f);   // + BIG*(1-mask_j)
        if (j == i)     vv = __fadd_rn(vv, 1e9f);   // + BIG*eye
        d2[j] = vv;
    }
    __syncthreads();
    for (int kk=0; kk<Kn; ++kk){
        float bv = __builtin_inff(); int bi = -1;
        for (int j=threadIdx.x; j<Nn; j+=256){
            float vv = d2[j];
            if (vv < bv){ bv = vv; bi = j; }   // ascending j => lowest idx kept on ties
        }
        rv[threadIdx.x] = bv; ri[threadIdx.x] = bi;
        __syncthreads();
        for (int s=128; s>0; s>>=1){
            if (threadIdx.x < s){
                float ov = rv[threadIdx.x+s]; int oi = ri[threadIdx.x+s];
                if (ov < rv[threadIdx.x] || (ov == rv[threadIdx.x] && oi < ri[threadIdx.x])){
                    rv[threadIdx.x] = ov; ri[threadIdx.x] = oi;
                }
            }
            __syncthreads();
        }
        if (threadIdx.x == 0){
            int wj = ri[0];
            eidx  [(size_t)blockIdx.x*Kn + kk] = wj;
            eidx_f[(size_t)blockIdx.x*Kn + kk] = (float)wj;
            d2[wj] = __builtin_inff();
        }
        __syncthreads();
    }
}

// ---------------- K3: edge features -> edge_h0, mask_ij ----------------
__global__ __launch_bounds__(128) void k_edge(
    const float* __restrict__ Xc, const float* __restrict__ Rm,
    const int* __restrict__ eidx, const int* __restrict__ C,
    const float* __restrict__ We, const float* __restrict__ be,
    float* __restrict__ edge_h, float* __restrict__ mask_ij_out)
{
    int e = blockIdx.x;
    int c = threadIdx.x;   // 128 = DE
    int b   = e / (Nn*Kn);
    int rem = e % (Nn*Kn);
    int n   = rem / Kn;
    int j   = eidx[e];
    int ib = b*Nn + n;
    int jb = b*Nn + j;
    __shared__ float feat[28];
    __shared__ float sRi[9], sRj[9];
    if (c < 9){ sRi[c] = Rm[ib*9+c]; sRj[c] = Rm[jb*9+c]; }
    __syncthreads();
    float d0 = Xc[jb*3+0]-Xc[ib*3+0];
    float d1 = Xc[jb*3+1]-Xc[ib*3+1];
    float d2v= Xc[jb*3+2]-Xc[ib*3+2];
    float dist = sqrtf(d0*d0+d1*d1+d2v*d2v);
    if (c < 28){
        float val;
        if (c < 16){
            float ctr = (20.f/15.f)*(float)c;
            float t = (dist - ctr)*(1.f/1.25f);
            val = expf(-t*t);
        } else if (c < 19){
            int cc = c-16;
            float loc = sRi[0*3+cc]*d0 + sRi[1*3+cc]*d1 + sRi[2*3+cc]*d2v;
            val = loc/(dist+EPSF);
        } else {
            int q = c-19; int ee = q/3, ff = q%3;
            val = sRi[0+ee]*sRj[0+ff] + sRi[3+ee]*sRj[3+ff] + sRi[6+ee]*sRj[6+ff];
        }
        feat[c] = val;
    }
    __syncthreads();
    float mij = (C[ib] > 0 && C[jb] > 0) ? 1.f : 0.f;
    float acc = be[c];
    #pragma unroll
    for (int f=0; f<28; ++f) acc += feat[f]*We[f*DEc + c];
    edge_h[(size_t)e*DEc + c] = acc*mij;
    if (c == 0) mask_ij_out[e] = mij;
}

// ---------------- K4: H1 = softplus(MI @ [Wm1|Wue1] + bias), tiled 64x64 ----------------
__global__ __launch_bounds__(256) void k_h1(
    const float* __restrict__ node_h, const float* __restrict__ edge_h,
    const int* __restrict__ eidx,
    const float* __restrict__ Wm1l, const float* __restrict__ Wue1l,
    const float* __restrict__ bm1l, const float* __restrict__ bue1l,
    float* __restrict__ H1, int row0)
{
    __shared__ float As[16][64];
    __shared__ float Bs[16][64];
    int tid = threadIdx.x;
    int rowBase = row0 + blockIdx.x*64;
    int colBase = blockIdx.y*64;

    // A-row decode (row fixed per thread)
    int arow = tid & 63; int ag = tid >> 6;
    int r = rowBase + arow;
    int b   = r / (Nn*Kn);
    int rem = r % (Nn*Kn);
    int n   = rem / Kn;
    int jn  = eidx[r];
    const float* hi = node_h + (size_t)(b*Nn+n )*DNc;
    const float* hj = node_h + (size_t)(b*Nn+jn)*DNc;
    const float* eh = edge_h + (size_t)r*DEc;

    // B pointer (uniform per block: 64-col tiles never span the 256 boundary)
    int bcol = tid & 63; int bg = tid >> 6;
    int gcol = colBase + bcol;
    const float* Wp; int ldw;
    if (gcol < 256){ Wp = Wm1l  + gcol;        ldw = DNc; }
    else           { Wp = Wue1l + (gcol-256);  ldw = DEc; }

    int tx = tid & 15, ty = tid >> 4;
    float acc[4][4] = {{0.f}};

    for (int k0=0; k0<640; k0+=16){
        int kb = k0 + ag*4;
        const float* src;
        if (kb < 256)      src = hi + kb;
        else if (kb < 512) src = hj + (kb-256);
        else               src = eh + (kb-512);
        float4 av = *(const float4*)src;
        As[ag*4+0][arow] = av.x;
        As[ag*4+1][arow] = av.y;
        As[ag*4+2][arow] = av.z;
        As[ag*4+3][arow] = av.w;
        #pragma unroll
        for (int t=0;t<4;++t) Bs[bg*4+t][bcol] = Wp[(size_t)(k0 + bg*4 + t)*ldw];
        __syncthreads();
        #pragma unroll
        for (int kk=0; kk<16; ++kk){
            float aa[4], bb[4];
            #pragma unroll
            for (int i2=0;i2<4;++i2) aa[i2] = As[kk][ty*4+i2];
            #pragma unroll
            for (int j2=0;j2<4;++j2) bb[j2] = Bs[kk][tx*4+j2];
            #pragma unroll
            for (int i2=0;i2<4;++i2)
                #pragma unroll
                for (int j2=0;j2<4;++j2) acc[i2][j2] += aa[i2]*bb[j2];
        }
        __syncthreads();
    }
    // epilogue: softplus(acc + bias) -> H1 (chunk-local rows), float4 stores
    float bias[4];
    #pragma unroll
    for (int j2=0;j2<4;++j2){
        int gc = colBase + tx*4 + j2;
        bias[j2] = (gc < 256) ? bm1l[gc] : bue1l[gc-256];
    }
    #pragma unroll
    for (int i2=0;i2<4;++i2){
        int gr = rowBase + ty*4 + i2;
        float4 q;
        q.x = softplusf(acc[i2][0] + bias[0]);
        q.y = softplusf(acc[i2][1] + bias[1]);
        q.z = softplusf(acc[i2][2] + bias[2]);
        q.w = softplusf(acc[i2][3] + bias[3]);
        *(float4*)(&H1[(size_t)(gr - row0)*384 + colBase + tx*4]) = q;
    }
}

// ---------------- K5: node update via S = sum_k mask*H1m, then S@Wm2 ----------------
__global__ __launch_bounds__(256) void k_node_upd(
    const float* __restrict__ H1, const float* __restrict__ Wm2l,
    const float* __restrict__ bm2l, const float* __restrict__ mask_ij,
    const float* __restrict__ mask_i,
    const float* __restrict__ node_cur, float* __restrict__ node_nxt, int node0)
{
    __shared__ float S[DNc];
    int lnid = blockIdx.x;
    int nid  = node0 + lnid;
    int c    = threadIdx.x;
    const float* mij = mask_ij + (size_t)nid*Kn;
    const float* h   = H1 + (size_t)lnid*Kn*384 + c;   // column c of H1m
    float cnt = 0.f, s = 0.f;
    #pragma unroll
    for (int k=0;k<Kn;++k){
        float mk = mij[k];
        cnt += mk;
        s   += mk * h[(size_t)k*384];
    }
    S[c] = s;
    __syncthreads();
    float acc = 0.f;
    #pragma unroll 8
    for (int j2=0;j2<DNc;++j2) acc += S[j2]*Wm2l[j2*DNc + c];
    float msum = acc + cnt*bm2l[c];
    float nh = node_cur[(size_t)nid*DNc + c];
    node_nxt[(size_t)nid*DNc + c] = (nh + msum/(cnt+EPSF)) * mask_i[nid];
}

// ---------------- K6: edge update: edge_h = (edge_h + H1e@Wue2 + bue2)*mask ----------------
__global__ __launch_bounds__(256) void k_edge_upd(
    const float* __restrict__ H1, const float* __restrict__ Wue2l,
    const float* __restrict__ bue2l, const float* __restrict__ mask_ij,
    float* __restrict__ edge_h, int row0)
{
    __shared__ float As[16][64];
    __shared__ float Bs[16][64];
    int tid = threadIdx.x;
    int rowBase = blockIdx.x*64;          // chunk-local
    int colBase = blockIdx.y*64;
    int arow = tid & 63; int ag = tid >> 6;
    int bcol = tid & 63; int bg = tid >> 6;
    const float* asrc = H1 + (size_t)(rowBase+arow)*384 + 256;
    int tx = tid & 15, ty = tid >> 4;
    float acc[4][4] = {{0.f}};
    for (int k0=0; k0<128; k0+=16){
        int kb = k0 + ag*4;
        float4 av = *(const float4*)(asrc + kb);
        As[ag*4+0][arow] = av.x;
        As[ag*4+1][arow] = av.y;
        As[ag*4+2][arow] = av.z;
        As[ag*4+3][arow] = av.w;
        #pragma unroll
        for (int t=0;t<4;++t) Bs[bg*4+t][bcol] = Wue2l[(size_t)(k0+bg*4+t)*DEc + colBase + bcol];
        __syncthreads();
        #pragma unroll
        for (int kk=0; kk<16; ++kk){
            float aa[4], bb[4];
            #pragma unroll
            for (int i2=0;i2<4;++i2) aa[i2] = As[kk][ty*4+i2];
            #pragma unroll
            for (int j2=0;j2<4;++j2) bb[j2] = Bs[kk][tx*4+j2];
            #pragma unroll
            for (int i2=0;i2<4;++i2)
                #pragma unroll
                for (int j2=0;j2<4;++j2) acc[i2][j2] += aa[i2]*bb[j2];
        }
        __syncthreads();
    }
    float bias[4];
    #pragma unroll
    for (int j2=0;j2<4;++j2) bias[j2] = bue2l[colBase + tx*4 + j2];
    #pragma unroll
    for (int i2=0;i2<4;++i2){
        int grl = rowBase + ty*4 + i2;        // chunk-local row
        int gr  = row0 + grl;                 // global edge row
        float mij = mask_ij[gr];
        float4* ep = (float4*)(&edge_h[(size_t)gr*DEc + colBase + tx*4]);
        float4 old = *ep;
        float4 q;
        q.x = (old.x + acc[i2][0] + bias[0])*mij;
        q.y = (old.y + acc[i2][1] + bias[1])*mij;
        q.z = (old.z + acc[i2][2] + bias[2])*mij;
        q.w = (old.w + acc[i2][3] + bias[3])*mij;
        *ep = q;
    }
}

extern "C" void kernel_launch(void* const* d_in, const int* in_sizes, int n_in,
                              void* d_out, int out_size, void* d_ws, size_t ws_size,
                              hipStream_t stream)
{
    (void)in_sizes; (void)n_in; (void)out_size; (void)ws_size;
    const float* X   = (const float*)d_in[0];
    const int*   C   = (const int*)  d_in[1];
    const float* Wn  = (const float*)d_in[2];
    const float* bn  = (const float*)d_in[3];
    const float* We  = (const float*)d_in[4];
    const float* be  = (const float*)d_in[5];
    const float* Wm1 = (const float*)d_in[6];
    const float* bm1 = (const float*)d_in[7];
    const float* Wm2 = (const float*)d_in[8];
    const float* bm2 = (const float*)d_in[9];
    const float* Wue1= (const float*)d_in[10];
    const float* bue1= (const float*)d_in[11];
    const float* Wue2= (const float*)d_in[12];
    const float* bue2= (const float*)d_in[13];

    float* out       = (float*)d_out;
    float* out_node  = out;                    // (B,N,DN)    1048576
    float* out_edge  = out + 1048576;          // (B,N,K,DE) 15728640
    float* out_eidxf = out + 16777216;         // (B,N,K)      122880 (as float)
    float* out_maski = out + 16900096;         // (B,N)          4096
    float* out_maskij= out + 16904192;         // (B,N,K)      122880

    float* ws    = (float*)d_ws;
    float* wXc   = ws;                         // 12288
    float* wR    = ws + 12288;                 // 36864
    float* wF    = ws + 49152;                 // 49152
    int*   wEidx = (int*)(ws + 98304);         // 122880 ints
    float* wNode2= ws + 221184;                // 1048576
    float* wH1   = ws + 1269760;               // 61440*384 = 23592960 (~94 MB chunked)

    k_geom <<<16,    256, 0, stream>>>(X, C, wXc, wR, wF, out_maski);
    k_nodeh<<<NODES, 256, 0, stream>>>(wF, Wn, bn, C, out_node);
    k_knn  <<<NODES, 256, 0, stream>>>(wXc, C, wEidx, out_eidxf);
    k_edge <<<EDGES, 128, 0, stream>>>(wXc, wR, wEidx, C, We, be, out_edge, out_maskij);

    float* cur = out_node;
    for (int l=0; l<3; ++l){
        float* nxt = (cur == out_node) ? wNode2 : out_node;
        for (int ch=0; ch<2; ++ch){
            int row0  = ch*61440;   // 2048 nodes * 30 edges
            int node0 = ch*2048;
            k_h1<<<dim3(960,6), 256, 0, stream>>>(cur, out_edge, wEidx,
                Wm1 + (size_t)l*640*256, Wue1 + (size_t)l*640*128,
                bm1 + l*256, bue1 + l*128, wH1, row0);
            k_node_upd<<<2048, 256, 0, stream>>>(wH1,
                Wm2 + (size_t)l*256*256, bm2 + l*256,
                out_maskij, out_maski, cur, nxt, node0);
            k_edge_upd<<<dim3(960,2), 256, 0, stream>>>(wH1,
                Wue2 + (size_t)l*128*128, bue2 + l*128,
                out_maskij, out_edge, row0);
        }
        cur = nxt;
    }
    if (cur != out_node){
        hipMemcpyAsync(out_node, cur, (size_t)1048576*sizeof(float),
                       hipMemcpyDeviceToDevice, stream);
    }
}

// Round 2
// 1631.933 us; speedup vs baseline: 2.0751x; 2.0751x over previous
//
#include <hip/hip_runtime.h>
#include <math.h>

#define Bdim 2
#define Nn   2048
#define Kn   30
#define DNc  256
#define DEc  128
#define NODES (Bdim*Nn)      // 4096
#define EDGES (Bdim*Nn*Kn)   // 122880
#define EPSF 1e-6f

#define NCHUNK 4
#define CH_EDGES (EDGES/NCHUNK)   // 30720
#define CH_NODES (NODES/NCHUNK)   // 1024

#define BK 64
#define LDA (BK+8)   // 72 bf16 elems per padded LDS row (144 B, 16B-aligned)

typedef __attribute__((ext_vector_type(8))) short short8;
typedef __attribute__((ext_vector_type(4))) float floatx4;

__device__ __forceinline__ float softplusf(float x){
    return fmaxf(x, 0.f) + log1pf(expf(-fabsf(x)));
}

__device__ __forceinline__ unsigned short f2bf(float x){
    union { float f; unsigned u; } v; v.f = x;
    unsigned r = v.u + 0x7fff + ((v.u >> 16) & 1);   // RNE
    return (unsigned short)(r >> 16);
}

// ---------------- K1: per-node geometry: Xc, R, 12-dim feat, mask ----------------
__global__ __launch_bounds__(256) void k_geom(
    const float* __restrict__ X, const int* __restrict__ C,
    float* __restrict__ Xc, float* __restrict__ Rm,
    float* __restrict__ feat, float* __restrict__ mask_out)
{
    int id = blockIdx.x*256 + threadIdx.x;
    if (id >= NODES) return;
    float a[4][3];
    #pragma unroll
    for (int t=0;t<4;++t)
        #pragma unroll
        for (int d=0;d<3;++d) a[t][d] = X[id*12 + t*3 + d];
    #pragma unroll
    for (int d=0; d<3; ++d){
        float s = __fadd_rn(__fadd_rn(__fadd_rn(a[0][d],a[1][d]),a[2][d]),a[3][d]);
        Xc[id*3+d] = __fmul_rn(s, 0.25f);
    }
    mask_out[id] = (C[id] > 0) ? 1.f : 0.f;

    float u[3], v[3], w[3], b2[3], v0[3], vv[3];
    #pragma unroll
    for (int d=0;d<3;++d) b2[d] = a[2][d]-a[1][d];
    float n2 = sqrtf(b2[0]*b2[0]+b2[1]*b2[1]+b2[2]*b2[2]);
    #pragma unroll
    for (int d=0;d<3;++d) u[d] = b2[d]/(n2+EPSF);
    #pragma unroll
    for (int d=0;d<3;++d) v0[d] = a[0][d]-a[1][d];
    float dt = v0[0]*u[0]+v0[1]*u[1]+v0[2]*u[2];
    #pragma unroll
    for (int d=0;d<3;++d) vv[d] = v0[d] - dt*u[d];
    float nv = sqrtf(vv[0]*vv[0]+vv[1]*vv[1]+vv[2]*vv[2]);
    #pragma unroll
    for (int d=0;d<3;++d) v[d] = vv[d]/(nv+EPSF);
    w[0] = u[1]*v[2]-u[2]*v[1];
    w[1] = u[2]*v[0]-u[0]*v[2];
    w[2] = u[0]*v[1]-u[1]*v[0];
    #pragma unroll
    for (int d=0;d<3;++d){
        Rm[id*9 + d*3 + 0] = u[d];
        Rm[id*9 + d*3 + 1] = v[d];
        Rm[id*9 + d*3 + 2] = w[d];
    }
    float bonds[3][3];
    #pragma unroll
    for (int d=0;d<3;++d){
        bonds[0][d] = a[1][d]-a[0][d];
        bonds[1][d] = b2[d];
        bonds[2][d] = a[3][d]-a[2][d];
    }
    #pragma unroll
    for (int bi=0;bi<3;++bi){
        float nb = sqrtf(bonds[bi][0]*bonds[bi][0]+bonds[bi][1]*bonds[bi][1]+bonds[bi][2]*bonds[bi][2]);
        #pragma unroll
        for (int d=0;d<3;++d) feat[id*12 + bi*4 + d] = bonds[bi][d]/(nb+EPSF);
        feat[id*12 + bi*4 + 3] = logf(nb+EPSF);
    }
}

// ---------------- K1b: node_h init ----------------
__global__ __launch_bounds__(256) void k_nodeh(
    const float* __restrict__ feat, const float* __restrict__ Wn,
    const float* __restrict__ bn, const int* __restrict__ C,
    float* __restrict__ node_h)
{
    int nid = blockIdx.x;
    int c   = threadIdx.x;
    __shared__ float f[12];
    if (c < 12) f[c] = feat[nid*12 + c];
    __syncthreads();
    float acc = bn[c];
    #pragma unroll
    for (int k=0;k<12;++k) acc += f[k]*Wn[k*DNc + c];
    float mask = (C[nid] > 0) ? 1.f : 0.f;
    node_h[nid*DNc + c] = acc*mask;
}

// ---------------- K2: kNN top-30 (exact top_k semantics) ----------------
__global__ __launch_bounds__(256) void k_knn(
    const float* __restrict__ Xc, const int* __restrict__ C,
    int* __restrict__ eidx, float* __restrict__ eidx_f)
{
    __shared__ float d2[Nn];
    __shared__ float rv[256];
    __shared__ int   ri[256];
    int b = blockIdx.x >> 11;
    int i = blockIdx.x & (Nn-1);
    const float* xcb = Xc + (size_t)b*Nn*3;
    const int*   Cb  = C  + (size_t)b*Nn;
    float xi0 = xcb[i*3+0], xi1 = xcb[i*3+1], xi2 = xcb[i*3+2];
    for (int j=threadIdx.x; j<Nn; j+=256){
        float dx = __fsub_rn(xi0, xcb[j*3+0]);
        float dy = __fsub_rn(xi1, xcb[j*3+1]);
        float dz = __fsub_rn(xi2, xcb[j*3+2]);
        float vv = __fadd_rn(__fadd_rn(__fmul_rn(dx,dx),__fmul_rn(dy,dy)),__fmul_rn(dz,dz));
        if (Cb[j] <= 0) vv = __fadd_rn(vv, 1e9f);
        if (j == i)     vv = __fadd_rn(vv, 1e9f);
        d2[j] = vv;
    }
    __syncthreads();
    for (int kk=0; kk<Kn; ++kk){
        float bv = __builtin_inff(); int bi = -1;
        for (int j=threadIdx.x; j<Nn; j+=256){
            float vv = d2[j];
            if (vv < bv){ bv = vv; bi = j; }
        }
        rv[threadIdx.x] = bv; ri[threadIdx.x] = bi;
        __syncthreads();
        for (int s=128; s>0; s>>=1){
            if (threadIdx.x < s){
                float ov = rv[threadIdx.x+s]; int oi = ri[threadIdx.x+s];
                if (ov < rv[threadIdx.x] || (ov == rv[threadIdx.x] && oi < ri[threadIdx.x])){
                    rv[threadIdx.x] = ov; ri[threadIdx.x] = oi;
                }
            }
            __syncthreads();
        }
        if (threadIdx.x == 0){
            int wj = ri[0];
            eidx  [(size_t)blockIdx.x*Kn + kk] = wj;
            eidx_f[(size_t)blockIdx.x*Kn + kk] = (float)wj;
            d2[wj] = __builtin_inff();
        }
        __syncthreads();
    }
}

// ---------------- K3: edge features -> edge_h0, mask_ij ----------------
__global__ __launch_bounds__(128) void k_edge(
    const float* __restrict__ Xc, const float* __restrict__ Rm,
    const int* __restrict__ eidx, const int* __restrict__ C,
    const float* __restrict__ We, const float* __restrict__ be,
    float* __restrict__ edge_h, float* __restrict__ mask_ij_out)
{
    int e = blockIdx.x;
    int c = threadIdx.x;
    int b   = e / (Nn*Kn);
    int rem = e % (Nn*Kn);
    int n   = rem / Kn;
    int j   = eidx[e];
    int ib = b*Nn + n;
    int jb = b*Nn + j;
    __shared__ float feat[28];
    __shared__ float sRi[9], sRj[9];
    if (c < 9){ sRi[c] = Rm[ib*9+c]; sRj[c] = Rm[jb*9+c]; }
    __syncthreads();
    float d0 = Xc[jb*3+0]-Xc[ib*3+0];
    float d1 = Xc[jb*3+1]-Xc[ib*3+1];
    float d2v= Xc[jb*3+2]-Xc[ib*3+2];
    float dist = sqrtf(d0*d0+d1*d1+d2v*d2v);
    if (c < 28){
        float val;
        if (c < 16){
            float ctr = (20.f/15.f)*(float)c;
            float t = (dist - ctr)*(1.f/1.25f);
            val = expf(-t*t);
        } else if (c < 19){
            int cc = c-16;
            float loc = sRi[0*3+cc]*d0 + sRi[1*3+cc]*d1 + sRi[2*3+cc]*d2v;
            val = loc/(dist+EPSF);
        } else {
            int q = c-19; int ee = q/3, ff = q%3;
            val = sRi[0+ee]*sRj[0+ff] + sRi[3+ee]*sRj[3+ff] + sRi[6+ee]*sRj[6+ff];
        }
        feat[c] = val;
    }
    __syncthreads();
    float mij = (C[ib] > 0 && C[jb] > 0) ? 1.f : 0.f;
    float acc = be[c];
    #pragma unroll
    for (int f=0; f<28; ++f) acc += feat[f]*We[f*DEc + c];
    edge_h[(size_t)e*DEc + c] = acc*mij;
    if (c == 0) mask_ij_out[e] = mij;
}

// ---------------- conversion / packing kernels ----------------
__global__ __launch_bounds__(256) void k_conv_bf16(
    const float* __restrict__ src, unsigned short* __restrict__ dst, int n4)
{
    int id = blockIdx.x*256 + threadIdx.x;
    if (id >= n4) return;
    float4 v = ((const float4*)src)[id];
    ushort4 o;
    o.x = f2bf(v.x); o.y = f2bf(v.y); o.z = f2bf(v.z); o.w = f2bf(v.w);
    ((ushort4*)dst)[id] = o;
}

// wPQw[l][n][k]: n in 0..767, k in 0..255; B^T pack of Wcat rows 0..511
__global__ __launch_bounds__(256) void k_pack_pqw(
    const float* __restrict__ Wm1, const float* __restrict__ Wue1,
    unsigned short* __restrict__ wPQw)
{
    int id = blockIdx.x*256 + threadIdx.x;
    if (id >= 3*768*256) return;
    int l = id / (768*256);
    int rem = id % (768*256);
    int n = rem >> 8, k = rem & 255;
    int c = (n < 384) ? n : n - 384;
    int r = (n < 384) ? k : 256 + k;
    float v = (c < 256) ? Wm1[((size_t)l*640 + r)*256 + c]
                        : Wue1[((size_t)l*640 + r)*128 + (c-256)];
    wPQw[id] = f2bf(v);
}

// wEw[l][n][k]: n in 0..383, k in 0..127; Wcat rows 512..639, transposed
__global__ __launch_bounds__(256) void k_pack_ew(
    const float* __restrict__ Wm1, const float* __restrict__ Wue1,
    unsigned short* __restrict__ wEw)
{
    int id = blockIdx.x*256 + threadIdx.x;
    if (id >= 3*384*128) return;
    int l = id / (384*128);
    int rem = id % (384*128);
    int n = rem >> 7, k = rem & 127;
    int r = 512 + k;
    float v = (n < 256) ? Wm1[((size_t)l*640 + r)*256 + n]
                        : Wue1[((size_t)l*640 + r)*128 + (n-256)];
    wEw[id] = f2bf(v);
}

// wUe2w[l][n][k] = Wue2[l][k][n]
__global__ __launch_bounds__(256) void k_pack_ue2(
    const float* __restrict__ Wue2, unsigned short* __restrict__ wUe2w)
{
    int id = blockIdx.x*256 + threadIdx.x;
    if (id >= 3*128*128) return;
    int l = id / (128*128);
    int rem = id % (128*128);
    int n = rem >> 7, k = rem & 127;
    wUe2w[id] = f2bf(Wue2[((size_t)l*128 + k)*128 + n]);
}

// ---------------- MFMA GEMM core helpers ----------------
__device__ __forceinline__ void stage_tile(
    const unsigned short* __restrict__ gbase, int ldg, int k0,
    unsigned short* lds, int tid)
{
    // 128 rows x 64 bf16 into padded LDS [row*LDA + k], 16B per thread x4
    #pragma unroll
    for (int it=0; it<4; ++it){
        int idx = it*256 + tid;
        int row = idx >> 3;
        int ke  = (idx & 7) * 8;
        const float4* src = (const float4*)(gbase + (size_t)row*ldg + k0 + ke);
        *(float4*)(&lds[row*LDA + ke]) = *src;
    }
}

__device__ __forceinline__ void mma_tile(
    const unsigned short* Als, const unsigned short* Bls,
    int wm, int wn, int lane, floatx4 acc[4][4])
{
    #pragma unroll
    for (int s=0; s<2; ++s){
        short8 af[4], bf[4];
        int kidx = s*32 + (lane>>4)*8;
        #pragma unroll
        for (int t=0;t<4;++t){
            int row = wm*64 + t*16 + (lane&15);
            af[t] = *(const short8*)(&Als[row*LDA + kidx]);
            int col = wn*64 + t*16 + (lane&15);
            bf[t] = *(const short8*)(&Bls[col*LDA + kidx]);
        }
        #pragma unroll
        for (int i=0;i<4;++i)
            #pragma unroll
            for (int j=0;j<4;++j)
                acc[i][j] = __builtin_amdgcn_mfma_f32_16x16x32_bf16(af[i], bf[j], acc[i][j], 0,0,0);
    }
}

// ---------------- K-PQ: PQ = node_h_bf16 @ wPQw^T, f32 out ----------------
__global__ __launch_bounds__(256) void k_pq(
    const unsigned short* __restrict__ A, const unsigned short* __restrict__ Bw,
    float* __restrict__ PQ)
{
    __shared__ __align__(16) unsigned short Als[128*LDA];
    __shared__ __align__(16) unsigned short Bls[128*LDA];
    int tid = threadIdx.x;
    int lane = tid & 63, wave = tid >> 6;
    int wm = wave >> 1, wn = wave & 1;
    const unsigned short* Ab = A + (size_t)blockIdx.x*128*256;
    const unsigned short* Bb = Bw + (size_t)blockIdx.y*128*256;
    floatx4 acc[4][4];
    #pragma unroll
    for (int i=0;i<4;++i)
        #pragma unroll
        for (int j=0;j<4;++j) acc[i][j] = (floatx4){0.f,0.f,0.f,0.f};
    for (int k0=0; k0<256; k0+=BK){
        stage_tile(Ab, 256, k0, Als, tid);
        stage_tile(Bb, 256, k0, Bls, tid);
        __syncthreads();
        mma_tile(Als, Bls, wm, wn, lane, acc);
        __syncthreads();
    }
    int quad = lane >> 4, cl = lane & 15;
    #pragma unroll
    for (int i=0;i<4;++i){
        #pragma unroll
        for (int rg=0;rg<4;++rg){
            int row = blockIdx.x*128 + wm*64 + i*16 + quad*4 + rg;
            #pragma unroll
            for (int j=0;j<4;++j){
                int col = blockIdx.y*128 + wn*64 + j*16 + cl;
                PQ[(size_t)row*768 + col] = acc[i][j][rg];
            }
        }
    }
}

// ---------------- K4: H1 = softplus(E + P[i] + Q[j] + bias) ----------------
__global__ __launch_bounds__(256) void k_h1(
    const unsigned short* __restrict__ Aeh,   // wEdgeBf16 + e0*128
    const unsigned short* __restrict__ Bw,    // wEw + l*384*128
    const float* __restrict__ PQ,
    const int* __restrict__ eidx,
    const float* __restrict__ bm1l, const float* __restrict__ bue1l,
    float* __restrict__ H1m, unsigned short* __restrict__ H1e, int e0)
{
    __shared__ __align__(16) unsigned short Als[128*LDA];
    __shared__ __align__(16) unsigned short Bls[128*LDA];
    int tid = threadIdx.x;
    int lane = tid & 63, wave = tid >> 6;
    int wm = wave >> 1, wn = wave & 1;
    const unsigned short* Ab = Aeh + (size_t)blockIdx.x*128*128;
    const unsigned short* Bb = Bw + (size_t)blockIdx.y*128*128;
    floatx4 acc[4][4];
    #pragma unroll
    for (int i=0;i<4;++i)
        #pragma unroll
        for (int j=0;j<4;++j) acc[i][j] = (floatx4){0.f,0.f,0.f,0.f};
    for (int k0=0; k0<128; k0+=BK){
        stage_tile(Ab, 128, k0, Als, tid);
        stage_tile(Bb, 128, k0, Bls, tid);
        __syncthreads();
        mma_tile(Als, Bls, wm, wn, lane, acc);
        __syncthreads();
    }
    int quad = lane >> 4, cl = lane & 15;
    int colblk = blockIdx.y;
    #pragma unroll
    for (int i=0;i<4;++i){
        #pragma unroll
        for (int rg=0;rg<4;++rg){
            int rl = blockIdx.x*128 + wm*64 + i*16 + quad*4 + rg; // chunk-local row
            int e  = e0 + rl;
            int ni = e / Kn;
            int bb = e / (Nn*Kn);
            int jg = bb*Nn + eidx[e];
            const float* Prow = PQ + (size_t)ni*768;
            const float* Qrow = PQ + (size_t)jg*768 + 384;
            #pragma unroll
            for (int j=0;j<4;++j){
                int col = colblk*128 + wn*64 + j*16 + cl;   // 0..383
                float v = acc[i][j][rg] + Prow[col] + Qrow[col];
                if (colblk < 2){
                    v = softplusf(v + bm1l[col]);
                    H1m[(size_t)rl*256 + col] = v;
                } else {
                    v = softplusf(v + bue1l[col-256]);
                    H1e[(size_t)rl*128 + (col-256)] = f2bf(v);
                }
            }
        }
    }
}

// ---------------- K5: node update (f32) ----------------
__global__ __launch_bounds__(256) void k_node_upd(
    const float* __restrict__ H1m, const float* __restrict__ Wm2l,
    const float* __restrict__ bm2l, const float* __restrict__ mask_ij,
    const float* __restrict__ mask_i,
    float* __restrict__ node_h, int node0)
{
    __shared__ float S[DNc];
    int lnid = blockIdx.x;
    int nid  = node0 + lnid;
    int c    = threadIdx.x;
    const float* mij = mask_ij + (size_t)nid*Kn;
    const float* h   = H1m + (size_t)lnid*Kn*256 + c;
    float cnt = 0.f, s = 0.f;
    #pragma unroll
    for (int k=0;k<Kn;++k){
        float mk = mij[k];
        cnt += mk;
        s   += mk * h[(size_t)k*256];
    }
    S[c] = s;
    __syncthreads();
    float acc = 0.f;
    #pragma unroll 8
    for (int j2=0;j2<DNc;++j2) acc += S[j2]*Wm2l[j2*DNc + c];
    float msum = acc + cnt*bm2l[c];
    float nh = node_h[(size_t)nid*DNc + c];
    node_h[(size_t)nid*DNc + c] = (nh + msum/(cnt+EPSF)) * mask_i[nid];
}

// ---------------- K6: edge update, MFMA ----------------
__global__ __launch_bounds__(256) void k_edge_upd(
    const unsigned short* __restrict__ H1e,   // chunk-local [30720][128]
    const unsigned short* __restrict__ Bw,    // wUe2w + l*128*128
    const float* __restrict__ bue2l, const float* __restrict__ mask_ij,
    float* __restrict__ edge_h, int e0)
{
    __shared__ __align__(16) unsigned short Als[128*LDA];
    __shared__ __align__(16) unsigned short Bls[128*LDA];
    int tid = threadIdx.x;
    int lane = tid & 63, wave = tid >> 6;
    int wm = wave >> 1, wn = wave & 1;
    const unsigned short* Ab = H1e + (size_t)blockIdx.x*128*128;
    floatx4 acc[4][4];
    #pragma unroll
    for (int i=0;i<4;++i)
        #pragma unroll
        for (int j=0;j<4;++j) acc[i][j] = (floatx4){0.f,0.f,0.f,0.f};
    for (int k0=0; k0<128; k0+=BK){
        stage_tile(Ab, 128, k0, Als, tid);
        stage_tile(Bw, 128, k0, Bls, tid);
        __syncthreads();
        mma_tile(Als, Bls, wm, wn, lane, acc);
        __syncthreads();
    }
    int quad = lane >> 4, cl = lane & 15;
    #pragma unroll
    for (int i=0;i<4;++i){
        #pragma unroll
        for (int rg=0;rg<4;++rg){
            int rl = blockIdx.x*128 + wm*64 + i*16 + quad*4 + rg;
            int e  = e0 + rl;
            float mij = mask_ij[e];
            #pragma unroll
            for (int j=0;j<4;++j){
                int col = wn*64 + j*16 + cl;   // 0..127
                float old = edge_h[(size_t)e*DEc + col];
                edge_h[(size_t)e*DEc + col] = (old + acc[i][j][rg] + bue2l[col]) * mij;
            }
        }
    }
}

extern "C" void kernel_launch(void* const* d_in, const int* in_sizes, int n_in,
                              void* d_out, int out_size, void* d_ws, size_t ws_size,
                              hipStream_t stream)
{
    (void)in_sizes; (void)n_in; (void)out_size; (void)ws_size;
    const float* X   = (const float*)d_in[0];
    const int*   C   = (const int*)  d_in[1];
    const float* Wn  = (const float*)d_in[2];
    const float* bn  = (const float*)d_in[3];
    const float* We  = (const float*)d_in[4];
    const float* be  = (const float*)d_in[5];
    const float* Wm1 = (const float*)d_in[6];
    const float* bm1 = (const float*)d_in[7];
    const float* Wm2 = (const float*)d_in[8];
    const float* bm2 = (const float*)d_in[9];
    const float* Wue1= (const float*)d_in[10];
    const float* bue1= (const float*)d_in[11];
    const float* Wue2= (const float*)d_in[12];
    const float* bue2= (const float*)d_in[13];

    float* out       = (float*)d_out;
    float* out_node  = out;                    // (B,N,DN)    1048576
    float* out_edge  = out + 1048576;          // (B,N,K,DE) 15728640
    float* out_eidxf = out + 16777216;         // (B,N,K)      122880 (as float)
    float* out_maski = out + 16900096;         // (B,N)          4096
    float* out_maskij= out + 16904192;         // (B,N,K)      122880

    char* wsb = (char*)d_ws;
    size_t off = 0;
    float* wXc   = (float*)(wsb + off); off += (size_t)12288*4;
    float* wR    = (float*)(wsb + off); off += (size_t)36864*4;
    float* wF    = (float*)(wsb + off); off += (size_t)49152*4;
    int*   wEidx = (int*)  (wsb + off); off += (size_t)122880*4;
    float* wPQ   = (float*)(wsb + off); off += (size_t)4096*768*4;          // 12.6 MB
    float* wH1m  = (float*)(wsb + off); off += (size_t)CH_EDGES*256*4;      // 31.5 MB
    unsigned short* wNodeBf = (unsigned short*)(wsb + off); off += (size_t)4096*256*2;
    unsigned short* wEdgeBf = (unsigned short*)(wsb + off); off += (size_t)EDGES*128*2; // 31.5 MB
    unsigned short* wH1e    = (unsigned short*)(wsb + off); off += (size_t)CH_EDGES*128*2;
    unsigned short* wPQw    = (unsigned short*)(wsb + off); off += (size_t)3*768*256*2;
    unsigned short* wEw     = (unsigned short*)(wsb + off); off += (size_t)3*384*128*2;
    unsigned short* wUe2w   = (unsigned short*)(wsb + off); off += (size_t)3*128*128*2;

    k_geom <<<16,    256, 0, stream>>>(X, C, wXc, wR, wF, out_maski);
    k_nodeh<<<NODES, 256, 0, stream>>>(wF, Wn, bn, C, out_node);
    k_knn  <<<NODES, 256, 0, stream>>>(wXc, C, wEidx, out_eidxf);
    k_edge <<<EDGES, 128, 0, stream>>>(wXc, wR, wEidx, C, We, be, out_edge, out_maskij);

    k_pack_pqw<<<(3*768*256+255)/256, 256, 0, stream>>>(Wm1, Wue1, wPQw);
    k_pack_ew <<<(3*384*128+255)/256, 256, 0, stream>>>(Wm1, Wue1, wEw);
    k_pack_ue2<<<(3*128*128+255)/256, 256, 0, stream>>>(Wue2, wUe2w);

    for (int l=0; l<3; ++l){
        k_conv_bf16<<<(4096*256/4+255)/256, 256, 0, stream>>>(out_node, wNodeBf, 4096*256/4);
        k_pq<<<dim3(32,6), 256, 0, stream>>>(wNodeBf, wPQw + (size_t)l*768*256, wPQ);
        k_conv_bf16<<<(EDGES*128/4+255)/256, 256, 0, stream>>>(out_edge, wEdgeBf, EDGES*128/4);
        for (int ch=0; ch<NCHUNK; ++ch){
            int e0    = ch*CH_EDGES;
            int node0 = ch*CH_NODES;
            k_h1<<<dim3(CH_EDGES/128,3), 256, 0, stream>>>(
                wEdgeBf + (size_t)e0*128, wEw + (size_t)l*384*128, wPQ, wEidx,
                bm1 + l*256, bue1 + l*128, wH1m, wH1e, e0);
            k_node_upd<<<CH_NODES, 256, 0, stream>>>(wH1m,
                Wm2 + (size_t)l*256*256, bm2 + l*256,
                out_maskij, out_maski, out_node, node0);
            k_edge_upd<<<CH_EDGES/128, 256, 0, stream>>>(wH1e,
                wUe2w + (size_t)l*128*128, bue2 + l*128,
                out_maskij, out_edge, e0);
        }
    }
}

// Round 4
// 1163.594 us; speedup vs baseline: 2.9103x; 1.4025x over previous
//
#include <hip/hip_runtime.h>
#include <math.h>

#define Bdim 2
#define Nn   2048
#define Kn   30
#define DNc  256
#define DEc  128
#define NODES (Bdim*Nn)      // 4096
#define EDGES (Bdim*Nn*Kn)   // 122880
#define EPSF 1e-6f

#define NCHUNK 2
#define CH_EDGES (EDGES/NCHUNK)   // 61440
#define CH_NODES (NODES/NCHUNK)   // 2048

#define BK 64
#define LDA (BK+8)   // padded LDS row (bf16 elems)

typedef __attribute__((ext_vector_type(8))) short short8;
typedef __attribute__((ext_vector_type(4))) float floatx4;

__device__ __forceinline__ float softplusf(float x){
    return fmaxf(x, 0.f) + log1pf(expf(-fabsf(x)));
}

__device__ __forceinline__ unsigned short f2bf(float x){
    union { float f; unsigned u; } v; v.f = x;
    unsigned r = v.u + 0x7fff + ((v.u >> 16) & 1);   // RNE
    return (unsigned short)(r >> 16);
}
__device__ __forceinline__ float bf2f(unsigned short h){
    union { unsigned u; float f; } v; v.u = ((unsigned)h) << 16;
    return v.f;
}

// ---------------- K1: per-node geometry ----------------
__global__ __launch_bounds__(256) void k_geom(
    const float* __restrict__ X, const int* __restrict__ C,
    float* __restrict__ Xc, float* __restrict__ Rm,
    float* __restrict__ feat, float* __restrict__ mask_out)
{
    int id = blockIdx.x*256 + threadIdx.x;
    if (id >= NODES) return;
    float a[4][3];
    #pragma unroll
    for (int t=0;t<4;++t)
        #pragma unroll
        for (int d=0;d<3;++d) a[t][d] = X[id*12 + t*3 + d];
    #pragma unroll
    for (int d=0; d<3; ++d){
        float s = __fadd_rn(__fadd_rn(__fadd_rn(a[0][d],a[1][d]),a[2][d]),a[3][d]);
        Xc[id*3+d] = __fmul_rn(s, 0.25f);
    }
    mask_out[id] = (C[id] > 0) ? 1.f : 0.f;

    float u[3], v[3], w[3], b2[3], v0[3], vv[3];
    #pragma unroll
    for (int d=0;d<3;++d) b2[d] = a[2][d]-a[1][d];
    float n2 = sqrtf(b2[0]*b2[0]+b2[1]*b2[1]+b2[2]*b2[2]);
    #pragma unroll
    for (int d=0;d<3;++d) u[d] = b2[d]/(n2+EPSF);
    #pragma unroll
    for (int d=0;d<3;++d) v0[d] = a[0][d]-a[1][d];
    float dt = v0[0]*u[0]+v0[1]*u[1]+v0[2]*u[2];
    #pragma unroll
    for (int d=0;d<3;++d) vv[d] = v0[d] - dt*u[d];
    float nv = sqrtf(vv[0]*vv[0]+vv[1]*vv[1]+vv[2]*vv[2]);
    #pragma unroll
    for (int d=0;d<3;++d) v[d] = vv[d]/(nv+EPSF);
    w[0] = u[1]*v[2]-u[2]*v[1];
    w[1] = u[2]*v[0]-u[0]*v[2];
    w[2] = u[0]*v[1]-u[1]*v[0];
    #pragma unroll
    for (int d=0;d<3;++d){
        Rm[id*9 + d*3 + 0] = u[d];
        Rm[id*9 + d*3 + 1] = v[d];
        Rm[id*9 + d*3 + 2] = w[d];
    }
    float bonds[3][3];
    #pragma unroll
    for (int d=0;d<3;++d){
        bonds[0][d] = a[1][d]-a[0][d];
        bonds[1][d] = b2[d];
        bonds[2][d] = a[3][d]-a[2][d];
    }
    #pragma unroll
    for (int bi=0;bi<3;++bi){
        float nb = sqrtf(bonds[bi][0]*bonds[bi][0]+bonds[bi][1]*bonds[bi][1]+bonds[bi][2]*bonds[bi][2]);
        #pragma unroll
        for (int d=0;d<3;++d) feat[id*12 + bi*4 + d] = bonds[bi][d]/(nb+EPSF);
        feat[id*12 + bi*4 + 3] = logf(nb+EPSF);
    }
}

// ---------------- K1b: node_h init (f32 + bf16) ----------------
__global__ __launch_bounds__(256) void k_nodeh(
    const float* __restrict__ feat, const float* __restrict__ Wn,
    const float* __restrict__ bn, const int* __restrict__ C,
    float* __restrict__ node_h, unsigned short* __restrict__ node_bf)
{
    int nid = blockIdx.x;
    int c   = threadIdx.x;
    __shared__ float f[12];
    if (c < 12) f[c] = feat[nid*12 + c];
    __syncthreads();
    float acc = bn[c];
    #pragma unroll
    for (int k=0;k<12;++k) acc += f[k]*Wn[k*DNc + c];
    float mask = (C[nid] > 0) ? 1.f : 0.f;
    float r = acc*mask;
    node_h[nid*DNc + c] = r;
    node_bf[nid*DNc + c] = f2bf(r);
}

// ---------------- K2: kNN top-30, wave-per-node, register selection ----------------
__global__ __launch_bounds__(256) void k_knn(
    const float* __restrict__ Xc, const int* __restrict__ C,
    int* __restrict__ eidx, float* __restrict__ eidx_f)
{
    __shared__ float sx[Nn], sy[Nn], sz[Nn], sadd[Nn];
    int tid  = threadIdx.x;
    int lane = tid & 63, wave = tid >> 6;
    int node0 = blockIdx.x*4;            // 4 nodes per block, same batch
    int base  = (node0 >> 11) << 11;     // batch base node
    for (int j=tid; j<Nn; j+=256){
        int gj = base + j;
        sx[j] = Xc[gj*3+0]; sy[j] = Xc[gj*3+1]; sz[j] = Xc[gj*3+2];
        sadd[j] = (C[gj] > 0) ? 0.f : 1e9f;
    }
    __syncthreads();

    int node = node0 + wave;
    int iloc = node & (Nn-1);
    float xi = sx[iloc], yi = sy[iloc], zi = sz[iloc];

    unsigned long long kreg[32];
    unsigned long long gm[8];
    #pragma unroll
    for (int t=0; t<32; ++t){
        int j = lane + t*64;
        float dx = __fsub_rn(xi, sx[j]);
        float dy = __fsub_rn(yi, sy[j]);
        float dz = __fsub_rn(zi, sz[j]);
        float vv = __fadd_rn(__fadd_rn(__fmul_rn(dx,dx),__fmul_rn(dy,dy)),__fmul_rn(dz,dz));
        vv = __fadd_rn(vv, sadd[j]);
        if (j == iloc) vv = __fadd_rn(vv, 1e9f);
        union { float f; unsigned u; } cv; cv.f = vv;
        kreg[t] = (((unsigned long long)cv.u) << 11) | (unsigned)j;
    }
    #pragma unroll
    for (int g=0; g<8; ++g){
        unsigned long long a = kreg[4*g+0], b = kreg[4*g+1];
        unsigned long long c = kreg[4*g+2], d = kreg[4*g+3];
        unsigned long long m1 = a<b?a:b, m2 = c<d?c:d;
        gm[g] = m1<m2?m1:m2;
    }
    unsigned long long m = gm[0]; int marg = 0;
    #pragma unroll
    for (int g=1; g<8; ++g) if (gm[g] < m){ m = gm[g]; marg = g; }

    for (int kk=0; kk<Kn; ++kk){
        unsigned long long best = m;
        #pragma unroll
        for (int d=1; d<64; d<<=1){
            unsigned long long o = __shfl_xor(best, d, 64);
            if (o < best) best = o;
        }
        if (lane == 0){
            int j = (int)(best & 2047ull);
            eidx  [(size_t)node*Kn + kk] = j;
            eidx_f[(size_t)node*Kn + kk] = (float)j;
        }
        if (m == best){
            #pragma unroll
            for (int g=0; g<8; ++g){
                if (marg == g){
                    #pragma unroll
                    for (int t=0; t<4; ++t)
                        if (kreg[4*g+t] == best) kreg[4*g+t] = ~0ull;
                    unsigned long long a = kreg[4*g+0], b = kreg[4*g+1];
                    unsigned long long c = kreg[4*g+2], d = kreg[4*g+3];
                    unsigned long long m1 = a<b?a:b, m2 = c<d?c:d;
                    gm[g] = m1<m2?m1:m2;
                }
            }
            m = gm[0]; marg = 0;
            #pragma unroll
            for (int g=1; g<8; ++g) if (gm[g] < m){ m = gm[g]; marg = g; }
        }
    }
}

// ---------------- K3: edge features (block per node) -> bf16 edge_h0, mask_ij ----------------
__global__ __launch_bounds__(256) void k_edge(
    const float* __restrict__ Xc, const float* __restrict__ Rm,
    const int* __restrict__ eidx, const int* __restrict__ C,
    const float* __restrict__ We, const float* __restrict__ be,
    unsigned short* __restrict__ edge_bf, float* __restrict__ mask_ij_out)
{
    __shared__ float sWe[28*128];
    __shared__ float sbe[128];
    __shared__ float sfeat[30][28];
    __shared__ float smij[30];
    __shared__ float sRi[9];
    int nid = blockIdx.x;
    int b   = nid >> 11;
    int tid = threadIdx.x;
    for (int idx=tid; idx<28*128; idx+=256) sWe[idx] = We[idx];
    if (tid < 128) sbe[tid] = be[tid];
    if (tid < 9)   sRi[tid] = Rm[nid*9 + tid];
    __syncthreads();
    if (tid < 30){
        int e  = nid*Kn + tid;
        int j  = eidx[e];
        int jb = (b<<11) + j;
        float d0 = Xc[jb*3+0]-Xc[nid*3+0];
        float d1 = Xc[jb*3+1]-Xc[nid*3+1];
        float d2v= Xc[jb*3+2]-Xc[nid*3+2];
        float dist = sqrtf(d0*d0+d1*d1+d2v*d2v);
        smij[tid] = (C[nid] > 0 && C[jb] > 0) ? 1.f : 0.f;
        #pragma unroll
        for (int c=0; c<16; ++c){
            float ctr = (20.f/15.f)*(float)c;
            float t = (dist - ctr)*(1.f/1.25f);
            sfeat[tid][c] = expf(-t*t);
        }
        #pragma unroll
        for (int cc=0; cc<3; ++cc){
            float loc = sRi[0*3+cc]*d0 + sRi[1*3+cc]*d1 + sRi[2*3+cc]*d2v;
            sfeat[tid][16+cc] = loc/(dist+EPSF);
        }
        float rj[9];
        #pragma unroll
        for (int q=0;q<9;++q) rj[q] = Rm[jb*9+q];
        #pragma unroll
        for (int ee=0; ee<3; ++ee)
            #pragma unroll
            for (int ff=0; ff<3; ++ff)
                sfeat[tid][19+ee*3+ff] = sRi[0+ee]*rj[0+ff] + sRi[3+ee]*rj[3+ff] + sRi[6+ee]*rj[6+ff];
        mask_ij_out[e] = smij[tid];
    }
    __syncthreads();
    int c  = tid & 127;
    int eg = tid >> 7;
    for (int e=eg; e<Kn; e+=2){
        float acc = sbe[c];
        #pragma unroll
        for (int f=0; f<28; ++f) acc += sfeat[e][f]*sWe[f*128 + c];
        edge_bf[(size_t)(nid*Kn + e)*DEc + c] = f2bf(acc * smij[e]);
    }
}

// ---------------- weight packing (bf16, B^T layouts) ----------------
__global__ __launch_bounds__(256) void k_pack_pqw(
    const float* __restrict__ Wm1, const float* __restrict__ Wue1,
    unsigned short* __restrict__ wPQw)
{
    int id = blockIdx.x*256 + threadIdx.x;
    if (id >= 3*768*256) return;
    int l = id / (768*256);
    int rem = id % (768*256);
    int n = rem >> 8, k = rem & 255;
    int c = (n < 384) ? n : n - 384;
    int r = (n < 384) ? k : 256 + k;
    float v = (c < 256) ? Wm1[((size_t)l*640 + r)*256 + c]
                        : Wue1[((size_t)l*640 + r)*128 + (c-256)];
    wPQw[id] = f2bf(v);
}

__global__ __launch_bounds__(256) void k_pack_ew(
    const float* __restrict__ Wm1, const float* __restrict__ Wue1,
    unsigned short* __restrict__ wEw)
{
    int id = blockIdx.x*256 + threadIdx.x;
    if (id >= 3*384*128) return;
    int l = id / (384*128);
    int rem = id % (384*128);
    int n = rem >> 7, k = rem & 127;
    int r = 512 + k;
    float v = (n < 256) ? Wm1[((size_t)l*640 + r)*256 + n]
                        : Wue1[((size_t)l*640 + r)*128 + (n-256)];
    wEw[id] = f2bf(v);
}

__global__ __launch_bounds__(256) void k_pack_ue2(
    const float* __restrict__ Wue2, unsigned short* __restrict__ wUe2w)
{
    int id = blockIdx.x*256 + threadIdx.x;
    if (id >= 3*128*128) return;
    int l = id / (128*128);
    int rem = id % (128*128);
    int n = rem >> 7, k = rem & 127;
    wUe2w[id] = f2bf(Wue2[((size_t)l*128 + k)*128 + n]);
}

__global__ __launch_bounds__(256) void k_pack_m2(
    const float* __restrict__ Wm2, unsigned short* __restrict__ wM2w)
{
    int id = blockIdx.x*256 + threadIdx.x;
    if (id >= 3*256*256) return;
    int l = id / (256*256);
    int rem = id % (256*256);
    int n = rem >> 8, k = rem & 255;
    wM2w[id] = f2bf(Wm2[((size_t)l*256 + k)*256 + n]);
}

// ---------------- MFMA GEMM helpers ----------------
__device__ __forceinline__ void stage_tile(
    const unsigned short* __restrict__ gbase, int ldg, int k0,
    unsigned short* lds, int tid)
{
    #pragma unroll
    for (int it=0; it<4; ++it){
        int idx = it*256 + tid;
        int row = idx >> 3;
        int ke  = (idx & 7) * 8;
        const float4* src = (const float4*)(gbase + (size_t)row*ldg + k0 + ke);
        *(float4*)(&lds[row*LDA + ke]) = *src;
    }
}

__device__ __forceinline__ void mma_tile(
    const unsigned short* Als, const unsigned short* Bls,
    int wm, int wn, int lane, floatx4 acc[4][4])
{
    #pragma unroll
    for (int s=0; s<2; ++s){
        short8 af[4], bf[4];
        int kidx = s*32 + (lane>>4)*8;
        #pragma unroll
        for (int t=0;t<4;++t){
            int row = wm*64 + t*16 + (lane&15);
            af[t] = *(const short8*)(&Als[row*LDA + kidx]);
            int col = wn*64 + t*16 + (lane&15);
            bf[t] = *(const short8*)(&Bls[col*LDA + kidx]);
        }
        #pragma unroll
        for (int i=0;i<4;++i)
            #pragma unroll
            for (int j=0;j<4;++j)
                acc[i][j] = __builtin_amdgcn_mfma_f32_16x16x32_bf16(af[i], bf[j], acc[i][j], 0,0,0);
    }
}

// ---------------- K-PQ: PQ = node_bf @ wPQw^T ----------------
__global__ __launch_bounds__(256) void k_pq(
    const unsigned short* __restrict__ A, const unsigned short* __restrict__ Bw,
    float* __restrict__ PQ)
{
    __shared__ __align__(16) unsigned short Als[128*LDA];
    __shared__ __align__(16) unsigned short Bls[128*LDA];
    int tid = threadIdx.x;
    int lane = tid & 63, wave = tid >> 6;
    int wm = wave >> 1, wn = wave & 1;
    const unsigned short* Ab = A + (size_t)blockIdx.x*128*256;
    const unsigned short* Bb = Bw + (size_t)blockIdx.y*128*256;
    floatx4 acc[4][4];
    #pragma unroll
    for (int i=0;i<4;++i)
        #pragma unroll
        for (int j=0;j<4;++j) acc[i][j] = (floatx4){0.f,0.f,0.f,0.f};
    for (int k0=0; k0<256; k0+=BK){
        stage_tile(Ab, 256, k0, Als, tid);
        stage_tile(Bb, 256, k0, Bls, tid);
        __syncthreads();
        mma_tile(Als, Bls, wm, wn, lane, acc);
        __syncthreads();
    }
    int quad = lane >> 4, cl = lane & 15;
    #pragma unroll
    for (int i=0;i<4;++i){
        #pragma unroll
        for (int rg=0;rg<4;++rg){
            int row = blockIdx.x*128 + wm*64 + i*16 + quad*4 + rg;
            #pragma unroll
            for (int j=0;j<4;++j){
                int col = blockIdx.y*128 + wn*64 + j*16 + cl;
                PQ[(size_t)row*768 + col] = acc[i][j][rg];
            }
        }
    }
}

// ---------------- K4: H1 = softplus(E + P[i] + Q[j] + bias), bf16 out ----------------
__global__ __launch_bounds__(256) void k_h1(
    const unsigned short* __restrict__ Aeh, const unsigned short* __restrict__ Bw,
    const float* __restrict__ PQ, const int* __restrict__ eidx,
    const float* __restrict__ bm1l, const float* __restrict__ bue1l,
    unsigned short* __restrict__ H1m, unsigned short* __restrict__ H1e, int e0)
{
    __shared__ __align__(16) unsigned short Als[128*LDA];
    __shared__ __align__(16) unsigned short Bls[128*LDA];
    int tid = threadIdx.x;
    int lane = tid & 63, wave = tid >> 6;
    int wm = wave >> 1, wn = wave & 1;
    const unsigned short* Ab = Aeh + (size_t)blockIdx.x*128*128;
    const unsigned short* Bb = Bw + (size_t)blockIdx.y*128*128;
    floatx4 acc[4][4];
    #pragma unroll
    for (int i=0;i<4;++i)
        #pragma unroll
        for (int j=0;j<4;++j) acc[i][j] = (floatx4){0.f,0.f,0.f,0.f};
    for (int k0=0; k0<128; k0+=BK){
        stage_tile(Ab, 128, k0, Als, tid);
        stage_tile(Bb, 128, k0, Bls, tid);
        __syncthreads();
        mma_tile(Als, Bls, wm, wn, lane, acc);
        __syncthreads();
    }
    int quad = lane >> 4, cl = lane & 15;
    int colblk = blockIdx.y;
    #pragma unroll
    for (int i=0;i<4;++i){
        #pragma unroll
        for (int rg=0;rg<4;++rg){
            int rl = blockIdx.x*128 + wm*64 + i*16 + quad*4 + rg;
            int e  = e0 + rl;
            int ni = e / Kn;
            int bb = e / (Nn*Kn);
            int jg = bb*Nn + eidx[e];
            const float* Prow = PQ + (size_t)ni*768;
            const float* Qrow = PQ + (size_t)jg*768 + 384;
            #pragma unroll
            for (int j=0;j<4;++j){
                int col = colblk*128 + wn*64 + j*16 + cl;
                float v = acc[i][j][rg] + Prow[col] + Qrow[col];
                if (colblk < 2){
                    v = softplusf(v + bm1l[col]);
                    H1m[(size_t)rl*256 + col] = f2bf(v);
                } else {
                    v = softplusf(v + bue1l[col-256]);
                    H1e[(size_t)rl*128 + (col-256)] = f2bf(v);
                }
            }
        }
    }
}

// ---------------- K5a: S = sum_k mask*H1m, cnt ----------------
__global__ __launch_bounds__(256) void k_s(
    const unsigned short* __restrict__ H1m, const float* __restrict__ mask_ij,
    unsigned short* __restrict__ S, float* __restrict__ cnt, int node0)
{
    int ln = blockIdx.x;
    int c  = threadIdx.x;
    int nid = node0 + ln;
    const float* mij = mask_ij + (size_t)nid*Kn;
    float s = 0.f, ct = 0.f;
    #pragma unroll
    for (int k=0;k<Kn;++k){
        float mk = mij[k];
        ct += mk;
        s  += mk * bf2f(H1m[((size_t)ln*Kn + k)*256 + c]);
    }
    S[(size_t)ln*256 + c] = f2bf(s);
    if (c == 0) cnt[ln] = ct;
}

// ---------------- K5b: node_h = (node_h + (S@Wm2 + cnt*bm2)/denom)*mask ----------------
__global__ __launch_bounds__(256) void k_node_gemm(
    const unsigned short* __restrict__ S, const unsigned short* __restrict__ Bw,
    const float* __restrict__ bm2l, const float* __restrict__ cnt,
    const float* __restrict__ mask_i,
    float* __restrict__ node_h, unsigned short* __restrict__ node_bf, int node0)
{
    __shared__ __align__(16) unsigned short Als[128*LDA];
    __shared__ __align__(16) unsigned short Bls[128*LDA];
    int tid = threadIdx.x;
    int lane = tid & 63, wave = tid >> 6;
    int wm = wave >> 1, wn = wave & 1;
    const unsigned short* Ab = S + (size_t)blockIdx.x*128*256;
    const unsigned short* Bb = Bw + (size_t)blockIdx.y*128*256;
    floatx4 acc[4][4];
    #pragma unroll
    for (int i=0;i<4;++i)
        #pragma unroll
        for (int j=0;j<4;++j) acc[i][j] = (floatx4){0.f,0.f,0.f,0.f};
    for (int k0=0; k0<256; k0+=BK){
        stage_tile(Ab, 256, k0, Als, tid);
        stage_tile(Bb, 256, k0, Bls, tid);
        __syncthreads();
        mma_tile(Als, Bls, wm, wn, lane, acc);
        __syncthreads();
    }
    int quad = lane >> 4, cl = lane & 15;
    #pragma unroll
    for (int i=0;i<4;++i){
        #pragma unroll
        for (int rg=0;rg<4;++rg){
            int rl  = blockIdx.x*128 + wm*64 + i*16 + quad*4 + rg;
            int nid = node0 + rl;
            float ct = cnt[rl];
            float mi = mask_i[nid];
            #pragma unroll
            for (int j=0;j<4;++j){
                int col = blockIdx.y*128 + wn*64 + j*16 + cl;
                float msum = acc[i][j][rg] + ct*bm2l[col];
                float nh = node_h[(size_t)nid*256 + col];
                float r = (nh + msum/(ct+EPSF))*mi;
                node_h[(size_t)nid*256 + col] = r;
                node_bf[(size_t)nid*256 + col] = f2bf(r);
            }
        }
    }
}

// ---------------- K6: edge residual update (bf16 master, f32 out on last layer) ----------------
// NOTE: edge_bf / edge_f32 are the UNOFFSET base pointers; indexing is global via e.
__global__ __launch_bounds__(256) void k_edge_upd(
    const unsigned short* __restrict__ H1e, const unsigned short* __restrict__ Bw,
    const float* __restrict__ bue2l, const float* __restrict__ mask_ij,
    unsigned short* __restrict__ edge_bf, float* __restrict__ edge_f32,
    int e0, int writeF32)
{
    __shared__ __align__(16) unsigned short Als[128*LDA];
    __shared__ __align__(16) unsigned short Bls[128*LDA];
    int tid = threadIdx.x;
    int lane = tid & 63, wave = tid >> 6;
    int wm = wave >> 1, wn = wave & 1;
    const unsigned short* Ab = H1e + (size_t)blockIdx.x*128*128;
    floatx4 acc[4][4];
    #pragma unroll
    for (int i=0;i<4;++i)
        #pragma unroll
        for (int j=0;j<4;++j) acc[i][j] = (floatx4){0.f,0.f,0.f,0.f};
    for (int k0=0; k0<128; k0+=BK){
        stage_tile(Ab, 128, k0, Als, tid);
        stage_tile(Bw, 128, k0, Bls, tid);
        __syncthreads();
        mma_tile(Als, Bls, wm, wn, lane, acc);
        __syncthreads();
    }
    int quad = lane >> 4, cl = lane & 15;
    #pragma unroll
    for (int i=0;i<4;++i){
        #pragma unroll
        for (int rg=0;rg<4;++rg){
            int rl = blockIdx.x*128 + wm*64 + i*16 + quad*4 + rg;
            int e  = e0 + rl;
            float mij = mask_ij[e];
            #pragma unroll
            for (int j=0;j<4;++j){
                int col = wn*64 + j*16 + cl;
                float old = bf2f(edge_bf[((size_t)e)*DEc + col]);
                float nv = (old + acc[i][j][rg] + bue2l[col]) * mij;
                edge_bf[((size_t)e)*DEc + col] = f2bf(nv);
                if (writeF32) edge_f32[((size_t)e)*DEc + col] = nv;
            }
        }
    }
}

extern "C" void kernel_launch(void* const* d_in, const int* in_sizes, int n_in,
                              void* d_out, int out_size, void* d_ws, size_t ws_size,
                              hipStream_t stream)
{
    (void)in_sizes; (void)n_in; (void)out_size; (void)ws_size;
    const float* X   = (const float*)d_in[0];
    const int*   C   = (const int*)  d_in[1];
    const float* Wn  = (const float*)d_in[2];
    const float* bn  = (const float*)d_in[3];
    const float* We  = (const float*)d_in[4];
    const float* be  = (const float*)d_in[5];
    const float* Wm1 = (const float*)d_in[6];
    const float* bm1 = (const float*)d_in[7];
    const float* Wm2 = (const float*)d_in[8];
    const float* bm2 = (const float*)d_in[9];
    const float* Wue1= (const float*)d_in[10];
    const float* bue1= (const float*)d_in[11];
    const float* Wue2= (const float*)d_in[12];
    const float* bue2= (const float*)d_in[13];

    float* out       = (float*)d_out;
    float* out_node  = out;                    // (B,N,DN)    1048576
    float* out_edge  = out + 1048576;          // (B,N,K,DE) 15728640
    float* out_eidxf = out + 16777216;         // (B,N,K)      122880
    float* out_maski = out + 16900096;         // (B,N)          4096
    float* out_maskij= out + 16904192;         // (B,N,K)      122880

    char* wsb = (char*)d_ws;
    size_t off = 0;
    float* wXc   = (float*)(wsb + off); off += (size_t)12288*4;
    float* wR    = (float*)(wsb + off); off += (size_t)36864*4;
    float* wF    = (float*)(wsb + off); off += (size_t)49152*4;
    int*   wEidx = (int*)  (wsb + off); off += (size_t)122880*4;
    float* wPQ   = (float*)(wsb + off); off += (size_t)4096*768*4;
    float* wCnt  = (float*)(wsb + off); off += (size_t)CH_NODES*4;
    unsigned short* wS      = (unsigned short*)(wsb + off); off += (size_t)CH_NODES*256*2;
    unsigned short* wNodeBf = (unsigned short*)(wsb + off); off += (size_t)4096*256*2;
    unsigned short* wEdgeBf = (unsigned short*)(wsb + off); off += (size_t)EDGES*128*2;
    unsigned short* wH1m    = (unsigned short*)(wsb + off); off += (size_t)CH_EDGES*256*2;
    unsigned short* wH1e    = (unsigned short*)(wsb + off); off += (size_t)CH_EDGES*128*2;
    unsigned short* wPQw    = (unsigned short*)(wsb + off); off += (size_t)3*768*256*2;
    unsigned short* wEw     = (unsigned short*)(wsb + off); off += (size_t)3*384*128*2;
    unsigned short* wUe2w   = (unsigned short*)(wsb + off); off += (size_t)3*128*128*2;
    unsigned short* wM2w    = (unsigned short*)(wsb + off); off += (size_t)3*256*256*2;

    k_geom <<<16,    256, 0, stream>>>(X, C, wXc, wR, wF, out_maski);
    k_nodeh<<<NODES, 256, 0, stream>>>(wF, Wn, bn, C, out_node, wNodeBf);
    k_knn  <<<NODES/4, 256, 0, stream>>>(wXc, C, wEidx, out_eidxf);
    k_edge <<<NODES, 256, 0, stream>>>(wXc, wR, wEidx, C, We, be, wEdgeBf, out_maskij);

    k_pack_pqw<<<(3*768*256+255)/256, 256, 0, stream>>>(Wm1, Wue1, wPQw);
    k_pack_ew <<<(3*384*128+255)/256, 256, 0, stream>>>(Wm1, Wue1, wEw);
    k_pack_ue2<<<(3*128*128+255)/256, 256, 0, stream>>>(Wue2, wUe2w);
    k_pack_m2 <<<(3*256*256+255)/256, 256, 0, stream>>>(Wm2, wM2w);

    for (int l=0; l<3; ++l){
        k_pq<<<dim3(32,6), 256, 0, stream>>>(wNodeBf, wPQw + (size_t)l*768*256, wPQ);
        for (int ch=0; ch<NCHUNK; ++ch){
            int e0    = ch*CH_EDGES;
            int node0 = ch*CH_NODES;
            k_h1<<<dim3(CH_EDGES/128,3), 256, 0, stream>>>(
                wEdgeBf + (size_t)e0*128, wEw + (size_t)l*384*128, wPQ, wEidx,
                bm1 + l*256, bue1 + l*128, wH1m, wH1e, e0);
            k_s<<<CH_NODES, 256, 0, stream>>>(wH1m, out_maskij, wS, wCnt, node0);
            k_node_gemm<<<dim3(CH_NODES/128,2), 256, 0, stream>>>(
                wS, wM2w + (size_t)l*256*256, bm2 + l*256, wCnt, out_maski,
                out_node, wNodeBf, node0);
            // FIX (R3 crash): pass UNOFFSET edge_bf/edge_f32 — kernel indexes globally by e=e0+rl.
            k_edge_upd<<<CH_EDGES/128, 256, 0, stream>>>(
                wH1e, wUe2w + (size_t)l*128*128, bue2 + l*128,
                out_maskij, wEdgeBf, out_edge,
                e0, (l==2) ? 1 : 0);
        }
    }
}

// Round 5
// 987.560 us; speedup vs baseline: 3.4291x; 1.1783x over previous
//
#include <hip/hip_runtime.h>
#include <math.h>

#define Bdim 2
#define Nn   2048
#define Kn   30
#define DNc  256
#define DEc  128
#define NODES (Bdim*Nn)      // 4096
#define EDGES (Bdim*Nn*Kn)   // 122880
#define EPSF 1e-6f

#define NCHUNK 2
#define CH_EDGES (EDGES/NCHUNK)   // 61440
#define CH_NODES (NODES/NCHUNK)   // 2048

#define BK 64
#define LDA (BK+8)    // padded GEMM LDS row (bf16 elems): 2-way on b128, ~free
#define LDP 140       // pqTile row stride (shorts): distinct bank offsets per quad

typedef __attribute__((ext_vector_type(8))) short short8;
typedef __attribute__((ext_vector_type(4))) float floatx4;

__device__ __forceinline__ float softplusf(float x){
    return fmaxf(x, 0.f) + log1pf(expf(-fabsf(x)));
}

__device__ __forceinline__ unsigned short f2bf(float x){
    union { float f; unsigned u; } v; v.f = x;
    unsigned r = v.u + 0x7fff + ((v.u >> 16) & 1);   // RNE
    return (unsigned short)(r >> 16);
}
__device__ __forceinline__ float bf2f(unsigned short h){
    union { unsigned u; float f; } v; v.u = ((unsigned)h) << 16;
    return v.f;
}

// ---------------- K1: per-node geometry ----------------
__global__ __launch_bounds__(256) void k_geom(
    const float* __restrict__ X, const int* __restrict__ C,
    float* __restrict__ Xc, float* __restrict__ Rm,
    float* __restrict__ feat, float* __restrict__ mask_out)
{
    int id = blockIdx.x*256 + threadIdx.x;
    if (id >= NODES) return;
    float a[4][3];
    #pragma unroll
    for (int t=0;t<4;++t)
        #pragma unroll
        for (int d=0;d<3;++d) a[t][d] = X[id*12 + t*3 + d];
    #pragma unroll
    for (int d=0; d<3; ++d){
        float s = __fadd_rn(__fadd_rn(__fadd_rn(a[0][d],a[1][d]),a[2][d]),a[3][d]);
        Xc[id*3+d] = __fmul_rn(s, 0.25f);
    }
    mask_out[id] = (C[id] > 0) ? 1.f : 0.f;

    float u[3], v[3], w[3], b2[3], v0[3], vv[3];
    #pragma unroll
    for (int d=0;d<3;++d) b2[d] = a[2][d]-a[1][d];
    float n2 = sqrtf(b2[0]*b2[0]+b2[1]*b2[1]+b2[2]*b2[2]);
    #pragma unroll
    for (int d=0;d<3;++d) u[d] = b2[d]/(n2+EPSF);
    #pragma unroll
    for (int d=0;d<3;++d) v0[d] = a[0][d]-a[1][d];
    float dt = v0[0]*u[0]+v0[1]*u[1]+v0[2]*u[2];
    #pragma unroll
    for (int d=0;d<3;++d) vv[d] = v0[d] - dt*u[d];
    float nv = sqrtf(vv[0]*vv[0]+vv[1]*vv[1]+vv[2]*vv[2]);
    #pragma unroll
    for (int d=0;d<3;++d) v[d] = vv[d]/(nv+EPSF);
    w[0] = u[1]*v[2]-u[2]*v[1];
    w[1] = u[2]*v[0]-u[0]*v[2];
    w[2] = u[0]*v[1]-u[1]*v[0];
    #pragma unroll
    for (int d=0;d<3;++d){
        Rm[id*9 + d*3 + 0] = u[d];
        Rm[id*9 + d*3 + 1] = v[d];
        Rm[id*9 + d*3 + 2] = w[d];
    }
    float bonds[3][3];
    #pragma unroll
    for (int d=0;d<3;++d){
        bonds[0][d] = a[1][d]-a[0][d];
        bonds[1][d] = b2[d];
        bonds[2][d] = a[3][d]-a[2][d];
    }
    #pragma unroll
    for (int bi=0;bi<3;++bi){
        float nb = sqrtf(bonds[bi][0]*bonds[bi][0]+bonds[bi][1]*bonds[bi][1]+bonds[bi][2]*bonds[bi][2]);
        #pragma unroll
        for (int d=0;d<3;++d) feat[id*12 + bi*4 + d] = bonds[bi][d]/(nb+EPSF);
        feat[id*12 + bi*4 + 3] = logf(nb+EPSF);
    }
}

// ---------------- K1b: node_h init (f32 + bf16) ----------------
__global__ __launch_bounds__(256) void k_nodeh(
    const float* __restrict__ feat, const float* __restrict__ Wn,
    const float* __restrict__ bn, const int* __restrict__ C,
    float* __restrict__ node_h, unsigned short* __restrict__ node_bf)
{
    int nid = blockIdx.x;
    int c   = threadIdx.x;
    __shared__ float f[12];
    if (c < 12) f[c] = feat[nid*12 + c];
    __syncthreads();
    float acc = bn[c];
    #pragma unroll
    for (int k=0;k<12;++k) acc += f[k]*Wn[k*DNc + c];
    float mask = (C[nid] > 0) ? 1.f : 0.f;
    float r = acc*mask;
    node_h[nid*DNc + c] = r;
    node_bf[nid*DNc + c] = f2bf(r);
}

// ---------------- K2: kNN top-30, wave-per-node, register selection ----------------
__global__ __launch_bounds__(256) void k_knn(
    const float* __restrict__ Xc, const int* __restrict__ C,
    int* __restrict__ eidx, float* __restrict__ eidx_f)
{
    __shared__ float sx[Nn], sy[Nn], sz[Nn], sadd[Nn];
    int tid  = threadIdx.x;
    int lane = tid & 63, wave = tid >> 6;
    int node0 = blockIdx.x*4;            // 4 nodes per block, same batch
    int base  = (node0 >> 11) << 11;     // batch base node
    for (int j=tid; j<Nn; j+=256){
        int gj = base + j;
        sx[j] = Xc[gj*3+0]; sy[j] = Xc[gj*3+1]; sz[j] = Xc[gj*3+2];
        sadd[j] = (C[gj] > 0) ? 0.f : 1e9f;
    }
    __syncthreads();

    int node = node0 + wave;
    int iloc = node & (Nn-1);
    float xi = sx[iloc], yi = sy[iloc], zi = sz[iloc];

    unsigned long long kreg[32];
    unsigned long long gm[8];
    #pragma unroll
    for (int t=0; t<32; ++t){
        int j = lane + t*64;
        float dx = __fsub_rn(xi, sx[j]);
        float dy = __fsub_rn(yi, sy[j]);
        float dz = __fsub_rn(zi, sz[j]);
        float vv = __fadd_rn(__fadd_rn(__fmul_rn(dx,dx),__fmul_rn(dy,dy)),__fmul_rn(dz,dz));
        vv = __fadd_rn(vv, sadd[j]);
        if (j == iloc) vv = __fadd_rn(vv, 1e9f);
        union { float f; unsigned u; } cv; cv.f = vv;
        kreg[t] = (((unsigned long long)cv.u) << 11) | (unsigned)j;
    }
    #pragma unroll
    for (int g=0; g<8; ++g){
        unsigned long long a = kreg[4*g+0], b = kreg[4*g+1];
        unsigned long long c = kreg[4*g+2], d = kreg[4*g+3];
        unsigned long long m1 = a<b?a:b, m2 = c<d?c:d;
        gm[g] = m1<m2?m1:m2;
    }
    unsigned long long m = gm[0]; int marg = 0;
    #pragma unroll
    for (int g=1; g<8; ++g) if (gm[g] < m){ m = gm[g]; marg = g; }

    for (int kk=0; kk<Kn; ++kk){
        unsigned long long best = m;
        #pragma unroll
        for (int d=1; d<64; d<<=1){
            unsigned long long o = __shfl_xor(best, d, 64);
            if (o < best) best = o;
        }
        if (lane == 0){
            int j = (int)(best & 2047ull);
            eidx  [(size_t)node*Kn + kk] = j;
            eidx_f[(size_t)node*Kn + kk] = (float)j;
        }
        if (m == best){
            #pragma unroll
            for (int g=0; g<8; ++g){
                if (marg == g){
                    #pragma unroll
                    for (int t=0; t<4; ++t)
                        if (kreg[4*g+t] == best) kreg[4*g+t] = ~0ull;
                    unsigned long long a = kreg[4*g+0], b = kreg[4*g+1];
                    unsigned long long c = kreg[4*g+2], d = kreg[4*g+3];
                    unsigned long long m1 = a<b?a:b, m2 = c<d?c:d;
                    gm[g] = m1<m2?m1:m2;
                }
            }
            m = gm[0]; marg = 0;
            #pragma unroll
            for (int g=1; g<8; ++g) if (gm[g] < m){ m = gm[g]; marg = g; }
        }
    }
}

// ---------------- K3: edge features -> bf16 edge_h0, mask_ij, eJg table ----------------
__global__ __launch_bounds__(256) void k_edge(
    const float* __restrict__ Xc, const float* __restrict__ Rm,
    const int* __restrict__ eidx, const int* __restrict__ C,
    const float* __restrict__ We, const float* __restrict__ be,
    unsigned short* __restrict__ edge_bf, float* __restrict__ mask_ij_out,
    int* __restrict__ eJg)
{
    __shared__ float sWe[28*128];
    __shared__ float sbe[128];
    __shared__ float sfeat[30][28];
    __shared__ float smij[30];
    __shared__ float sRi[9];
    int nid = blockIdx.x;
    int b   = nid >> 11;
    int tid = threadIdx.x;
    for (int idx=tid; idx<28*128; idx+=256) sWe[idx] = We[idx];
    if (tid < 128) sbe[tid] = be[tid];
    if (tid < 9)   sRi[tid] = Rm[nid*9 + tid];
    __syncthreads();
    if (tid < 30){
        int e  = nid*Kn + tid;
        int j  = eidx[e];
        int jb = (b<<11) + j;
        eJg[e] = jb;
        float d0 = Xc[jb*3+0]-Xc[nid*3+0];
        float d1 = Xc[jb*3+1]-Xc[nid*3+1];
        float d2v= Xc[jb*3+2]-Xc[nid*3+2];
        float dist = sqrtf(d0*d0+d1*d1+d2v*d2v);
        smij[tid] = (C[nid] > 0 && C[jb] > 0) ? 1.f : 0.f;
        #pragma unroll
        for (int c=0; c<16; ++c){
            float ctr = (20.f/15.f)*(float)c;
            float t = (dist - ctr)*(1.f/1.25f);
            sfeat[tid][c] = expf(-t*t);
        }
        #pragma unroll
        for (int cc=0; cc<3; ++cc){
            float loc = sRi[0*3+cc]*d0 + sRi[1*3+cc]*d1 + sRi[2*3+cc]*d2v;
            sfeat[tid][16+cc] = loc/(dist+EPSF);
        }
        float rj[9];
        #pragma unroll
        for (int q=0;q<9;++q) rj[q] = Rm[jb*9+q];
        #pragma unroll
        for (int ee=0; ee<3; ++ee)
            #pragma unroll
            for (int ff=0; ff<3; ++ff)
                sfeat[tid][19+ee*3+ff] = sRi[0+ee]*rj[0+ff] + sRi[3+ee]*rj[3+ff] + sRi[6+ee]*rj[6+ff];
        mask_ij_out[e] = smij[tid];
    }
    __syncthreads();
    int c  = tid & 127;
    int eg = tid >> 7;
    for (int e=eg; e<Kn; e+=2){
        float acc = sbe[c];
        #pragma unroll
        for (int f=0; f<28; ++f) acc += sfeat[e][f]*sWe[f*128 + c];
        edge_bf[(size_t)(nid*Kn + e)*DEc + c] = f2bf(acc * smij[e]);
    }
}

// ---------------- weight packing (bf16, B^T layouts) ----------------
__global__ __launch_bounds__(256) void k_pack_pqw(
    const float* __restrict__ Wm1, const float* __restrict__ Wue1,
    unsigned short* __restrict__ wPQw)
{
    int id = blockIdx.x*256 + threadIdx.x;
    if (id >= 3*768*256) return;
    int l = id / (768*256);
    int rem = id % (768*256);
    int n = rem >> 8, k = rem & 255;
    int c = (n < 384) ? n : n - 384;
    int r = (n < 384) ? k : 256 + k;
    float v = (c < 256) ? Wm1[((size_t)l*640 + r)*256 + c]
                        : Wue1[((size_t)l*640 + r)*128 + (c-256)];
    wPQw[id] = f2bf(v);
}

__global__ __launch_bounds__(256) void k_pack_ew(
    const float* __restrict__ Wm1, const float* __restrict__ Wue1,
    unsigned short* __restrict__ wEw)
{
    int id = blockIdx.x*256 + threadIdx.x;
    if (id >= 3*384*128) return;
    int l = id / (384*128);
    int rem = id % (384*128);
    int n = rem >> 7, k = rem & 127;
    int r = 512 + k;
    float v = (n < 256) ? Wm1[((size_t)l*640 + r)*256 + n]
                        : Wue1[((size_t)l*640 + r)*128 + (n-256)];
    wEw[id] = f2bf(v);
}

__global__ __launch_bounds__(256) void k_pack_ue2(
    const float* __restrict__ Wue2, unsigned short* __restrict__ wUe2w)
{
    int id = blockIdx.x*256 + threadIdx.x;
    if (id >= 3*128*128) return;
    int l = id / (128*128);
    int rem = id % (128*128);
    int n = rem >> 7, k = rem & 127;
    wUe2w[id] = f2bf(Wue2[((size_t)l*128 + k)*128 + n]);
}

__global__ __launch_bounds__(256) void k_pack_m2(
    const float* __restrict__ Wm2, unsigned short* __restrict__ wM2w)
{
    int id = blockIdx.x*256 + threadIdx.x;
    if (id >= 3*256*256) return;
    int l = id / (256*256);
    int rem = id % (256*256);
    int n = rem >> 8, k = rem & 255;
    wM2w[id] = f2bf(Wm2[((size_t)l*256 + k)*256 + n]);
}

// ---------------- MFMA GEMM helpers ----------------
__device__ __forceinline__ void stage_tile(
    const unsigned short* __restrict__ gbase, int ldg, int k0,
    unsigned short* lds, int tid)
{
    #pragma unroll
    for (int it=0; it<4; ++it){
        int idx = it*256 + tid;
        int row = idx >> 3;
        int ke  = (idx & 7) * 8;
        const float4* src = (const float4*)(gbase + (size_t)row*ldg + k0 + ke);
        *(float4*)(&lds[row*LDA + ke]) = *src;
    }
}

__device__ __forceinline__ void mma_tile(
    const unsigned short* Als, const unsigned short* Bls,
    int wm, int wn, int lane, floatx4 acc[4][4])
{
    #pragma unroll
    for (int s=0; s<2; ++s){
        short8 af[4], bf[4];
        int kidx = s*32 + (lane>>4)*8;
        #pragma unroll
        for (int t=0;t<4;++t){
            int row = wm*64 + t*16 + (lane&15);
            af[t] = *(const short8*)(&Als[row*LDA + kidx]);
            int col = wn*64 + t*16 + (lane&15);
            bf[t] = *(const short8*)(&Bls[col*LDA + kidx]);
        }
        #pragma unroll
        for (int i=0;i<4;++i)
            #pragma unroll
            for (int j=0;j<4;++j)
                acc[i][j] = __builtin_amdgcn_mfma_f32_16x16x32_bf16(af[i], bf[j], acc[i][j], 0,0,0);
    }
}

// ---------------- K-PQ: PQ(bf16) = node_bf @ wPQw^T ----------------
__global__ __launch_bounds__(256) void k_pq(
    const unsigned short* __restrict__ A, const unsigned short* __restrict__ Bw,
    unsigned short* __restrict__ PQbf)
{
    __shared__ __align__(16) unsigned short Als[128*LDA];
    __shared__ __align__(16) unsigned short Bls[128*LDA];
    int tid = threadIdx.x;
    int lane = tid & 63, wave = tid >> 6;
    int wm = wave >> 1, wn = wave & 1;
    const unsigned short* Ab = A + (size_t)blockIdx.x*128*256;
    const unsigned short* Bb = Bw + (size_t)blockIdx.y*128*256;
    floatx4 acc[4][4];
    #pragma unroll
    for (int i=0;i<4;++i)
        #pragma unroll
        for (int j=0;j<4;++j) acc[i][j] = (floatx4){0.f,0.f,0.f,0.f};
    for (int k0=0; k0<256; k0+=BK){
        stage_tile(Ab, 256, k0, Als, tid);
        stage_tile(Bb, 256, k0, Bls, tid);
        __syncthreads();
        mma_tile(Als, Bls, wm, wn, lane, acc);
        __syncthreads();
    }
    int quad = lane >> 4, cl = lane & 15;
    #pragma unroll
    for (int i=0;i<4;++i){
        #pragma unroll
        for (int rg=0;rg<4;++rg){
            int row = blockIdx.x*128 + wm*64 + i*16 + quad*4 + rg;
            #pragma unroll
            for (int j=0;j<4;++j){
                int col = blockIdx.y*128 + wn*64 + j*16 + cl;
                PQbf[(size_t)row*768 + col] = f2bf(acc[i][j][rg]);
            }
        }
    }
}

// ---------------- K4: H1 = softplus(E + P[i] + Q[j] + bias), LDS-staged epilogue ----------------
__global__ __launch_bounds__(256) void k_h1(
    const unsigned short* __restrict__ Aeh, const unsigned short* __restrict__ Bw,
    const unsigned short* __restrict__ PQbf, const int* __restrict__ eJg,
    const float* __restrict__ bm1l, const float* __restrict__ bue1l,
    unsigned short* __restrict__ H1m, unsigned short* __restrict__ H1e, int e0)
{
    __shared__ __align__(16) unsigned short Als[128*LDA];
    __shared__ __align__(16) unsigned short Bls[128*LDA];
    __shared__ __align__(16) unsigned short pqTile[128*LDP];
    int tid = threadIdx.x;
    int lane = tid & 63, wave = tid >> 6;
    int wm = wave >> 1, wn = wave & 1;
    int colblk = blockIdx.y;

    // ---- phase 1: cooperative PQ gather -> pqTile (visible after GEMM's barriers) ----
    {
        int rl = tid >> 1;
        int h  = tid & 1;
        int e  = e0 + blockIdx.x*128 + rl;
        int ni = e / Kn;
        int jg = eJg[e];
        int cb = colblk*128 + h*64;
        const unsigned short* Pr = PQbf + (size_t)ni*768 + cb;
        const unsigned short* Qr = PQbf + (size_t)jg*768 + 384 + cb;
        #pragma unroll
        for (int q=0; q<8; ++q){
            short8 pv = *(const short8*)(Pr + q*8);
            short8 qv = *(const short8*)(Qr + q*8);
            short8 ov;
            #pragma unroll
            for (int z=0; z<8; ++z)
                ov[z] = (short)f2bf(bf2f((unsigned short)pv[z]) + bf2f((unsigned short)qv[z]));
            *(short8*)(&pqTile[rl*LDP + h*64 + q*8]) = ov;
        }
    }

    // ---- GEMM: E-tile @ W ----
    const unsigned short* Ab = Aeh + (size_t)blockIdx.x*128*128;
    const unsigned short* Bb = Bw + (size_t)colblk*128*128;
    floatx4 acc[4][4];
    #pragma unroll
    for (int i=0;i<4;++i)
        #pragma unroll
        for (int j=0;j<4;++j) acc[i][j] = (floatx4){0.f,0.f,0.f,0.f};
    for (int k0=0; k0<128; k0+=BK){
        stage_tile(Ab, 128, k0, Als, tid);
        stage_tile(Bb, 128, k0, Bls, tid);
        __syncthreads();
        mma_tile(Als, Bls, wm, wn, lane, acc);
        __syncthreads();
    }

    // ---- phase 2: epilogue from LDS, in-place (sole-owner) overwrite ----
    int quad = lane >> 4, cl = lane & 15;
    float bias[4];
    #pragma unroll
    for (int j=0;j<4;++j){
        int col = colblk*128 + wn*64 + j*16 + cl;
        bias[j] = (colblk < 2) ? bm1l[col] : bue1l[col-256];
    }
    #pragma unroll
    for (int i=0;i<4;++i){
        #pragma unroll
        for (int rg=0;rg<4;++rg){
            int rowl = wm*64 + i*16 + quad*4 + rg;
            #pragma unroll
            for (int j=0;j<4;++j){
                int coll = wn*64 + j*16 + cl;
                float pq = bf2f(pqTile[rowl*LDP + coll]);
                float v = softplusf(acc[i][j][rg] + pq + bias[j]);
                pqTile[rowl*LDP + coll] = f2bf(v);
            }
        }
    }
    __syncthreads();

    // ---- cooperative vector stores ----
    {
        int rl = tid >> 1;
        int h  = tid & 1;
        int rglob = blockIdx.x*128 + rl;   // chunk-local row
        if (colblk < 2){
            unsigned short* dst = H1m + (size_t)rglob*256 + colblk*128 + h*64;
            #pragma unroll
            for (int q=0; q<8; ++q)
                *(short8*)(dst + q*8) = *(const short8*)(&pqTile[rl*LDP + h*64 + q*8]);
        } else {
            unsigned short* dst = H1e + (size_t)rglob*128 + h*64;
            #pragma unroll
            for (int q=0; q<8; ++q)
                *(short8*)(dst + q*8) = *(const short8*)(&pqTile[rl*LDP + h*64 + q*8]);
        }
    }
}

// ---------------- K5a: S = sum_k mask*H1m, cnt ----------------
__global__ __launch_bounds__(256) void k_s(
    const unsigned short* __restrict__ H1m, const float* __restrict__ mask_ij,
    unsigned short* __restrict__ S, float* __restrict__ cnt, int node0)
{
    int ln = blockIdx.x;
    int c  = threadIdx.x;
    int nid = node0 + ln;
    const float* mij = mask_ij + (size_t)nid*Kn;
    float s = 0.f, ct = 0.f;
    #pragma unroll
    for (int k=0;k<Kn;++k){
        float mk = mij[k];
        ct += mk;
        s  += mk * bf2f(H1m[((size_t)ln*Kn + k)*256 + c]);
    }
    S[(size_t)ln*256 + c] = f2bf(s);
    if (c == 0) cnt[ln] = ct;
}

// ---------------- K5b: node_h = (node_h + (S@Wm2 + cnt*bm2)/denom)*mask ----------------
__global__ __launch_bounds__(256) void k_node_gemm(
    const unsigned short* __restrict__ S, const unsigned short* __restrict__ Bw,
    const float* __restrict__ bm2l, const float* __restrict__ cnt,
    const float* __restrict__ mask_i,
    float* __restrict__ node_h, unsigned short* __restrict__ node_bf, int node0)
{
    __shared__ __align__(16) unsigned short Als[128*LDA];
    __shared__ __align__(16) unsigned short Bls[128*LDA];
    int tid = threadIdx.x;
    int lane = tid & 63, wave = tid >> 6;
    int wm = wave >> 1, wn = wave & 1;
    const unsigned short* Ab = S + (size_t)blockIdx.x*128*256;
    const unsigned short* Bb = Bw + (size_t)blockIdx.y*128*256;
    floatx4 acc[4][4];
    #pragma unroll
    for (int i=0;i<4;++i)
        #pragma unroll
        for (int j=0;j<4;++j) acc[i][j] = (floatx4){0.f,0.f,0.f,0.f};
    for (int k0=0; k0<256; k0+=BK){
        stage_tile(Ab, 256, k0, Als, tid);
        stage_tile(Bb, 256, k0, Bls, tid);
        __syncthreads();
        mma_tile(Als, Bls, wm, wn, lane, acc);
        __syncthreads();
    }
    int quad = lane >> 4, cl = lane & 15;
    #pragma unroll
    for (int i=0;i<4;++i){
        #pragma unroll
        for (int rg=0;rg<4;++rg){
            int rl  = blockIdx.x*128 + wm*64 + i*16 + quad*4 + rg;
            int nid = node0 + rl;
            float ct = cnt[rl];
            float mi = mask_i[nid];
            #pragma unroll
            for (int j=0;j<4;++j){
                int col = blockIdx.y*128 + wn*64 + j*16 + cl;
                float msum = acc[i][j][rg] + ct*bm2l[col];
                float nh = node_h[(size_t)nid*256 + col];
                float r = (nh + msum/(ct+EPSF))*mi;
                node_h[(size_t)nid*256 + col] = r;
                node_bf[(size_t)nid*256 + col] = f2bf(r);
            }
        }
    }
}

// ---------------- K6: edge residual update (bf16 master, f32 out on last layer) ----------------
// NOTE: edge_bf / edge_f32 are UNOFFSET base pointers; indexing is global via e.
__global__ __launch_bounds__(256) void k_edge_upd(
    const unsigned short* __restrict__ H1e, const unsigned short* __restrict__ Bw,
    const float* __restrict__ bue2l, const float* __restrict__ mask_ij,
    unsigned short* __restrict__ edge_bf, float* __restrict__ edge_f32,
    int e0, int writeF32)
{
    __shared__ __align__(16) unsigned short Als[128*LDA];
    __shared__ __align__(16) unsigned short Bls[128*LDA];
    int tid = threadIdx.x;
    int lane = tid & 63, wave = tid >> 6;
    int wm = wave >> 1, wn = wave & 1;
    const unsigned short* Ab = H1e + (size_t)blockIdx.x*128*128;
    floatx4 acc[4][4];
    #pragma unroll
    for (int i=0;i<4;++i)
        #pragma unroll
        for (int j=0;j<4;++j) acc[i][j] = (floatx4){0.f,0.f,0.f,0.f};
    for (int k0=0; k0<128; k0+=BK){
        stage_tile(Ab, 128, k0, Als, tid);
        stage_tile(Bw, 128, k0, Bls, tid);
        __syncthreads();
        mma_tile(Als, Bls, wm, wn, lane, acc);
        __syncthreads();
    }
    int quad = lane >> 4, cl = lane & 15;
    #pragma unroll
    for (int i=0;i<4;++i){
        #pragma unroll
        for (int rg=0;rg<4;++rg){
            int rl = blockIdx.x*128 + wm*64 + i*16 + quad*4 + rg;
            int e  = e0 + rl;
            float mij = mask_ij[e];
            #pragma unroll
            for (int j=0;j<4;++j){
                int col = wn*64 + j*16 + cl;
                float old = bf2f(edge_bf[((size_t)e)*DEc + col]);
                float nv = (old + acc[i][j][rg] + bue2l[col]) * mij;
                edge_bf[((size_t)e)*DEc + col] = f2bf(nv);
                if (writeF32) edge_f32[((size_t)e)*DEc + col] = nv;
            }
        }
    }
}

extern "C" void kernel_launch(void* const* d_in, const int* in_sizes, int n_in,
                              void* d_out, int out_size, void* d_ws, size_t ws_size,
                              hipStream_t stream)
{
    (void)in_sizes; (void)n_in; (void)out_size; (void)ws_size;
    const float* X   = (const float*)d_in[0];
    const int*   C   = (const int*)  d_in[1];
    const float* Wn  = (const float*)d_in[2];
    const float* bn  = (const float*)d_in[3];
    const float* We  = (const float*)d_in[4];
    const float* be  = (const float*)d_in[5];
    const float* Wm1 = (const float*)d_in[6];
    const float* bm1 = (const float*)d_in[7];
    const float* Wm2 = (const float*)d_in[8];
    const float* bm2 = (const float*)d_in[9];
    const float* Wue1= (const float*)d_in[10];
    const float* bue1= (const float*)d_in[11];
    const float* Wue2= (const float*)d_in[12];
    const float* bue2= (const float*)d_in[13];

    float* out       = (float*)d_out;
    float* out_node  = out;                    // (B,N,DN)    1048576
    float* out_edge  = out + 1048576;          // (B,N,K,DE) 15728640
    float* out_eidxf = out + 16777216;         // (B,N,K)      122880
    float* out_maski = out + 16900096;         // (B,N)          4096
    float* out_maskij= out + 16904192;         // (B,N,K)      122880

    char* wsb = (char*)d_ws;
    size_t off = 0;
    float* wXc   = (float*)(wsb + off); off += (size_t)12288*4;
    float* wR    = (float*)(wsb + off); off += (size_t)36864*4;
    float* wF    = (float*)(wsb + off); off += (size_t)49152*4;
    int*   wEidx = (int*)  (wsb + off); off += (size_t)122880*4;
    int*   wJg   = (int*)  (wsb + off); off += (size_t)122880*4;
    float* wCnt  = (float*)(wsb + off); off += (size_t)CH_NODES*4;
    unsigned short* wPQ     = (unsigned short*)(wsb + off); off += (size_t)4096*768*2;
    unsigned short* wS      = (unsigned short*)(wsb + off); off += (size_t)CH_NODES*256*2;
    unsigned short* wNodeBf = (unsigned short*)(wsb + off); off += (size_t)4096*256*2;
    unsigned short* wEdgeBf = (unsigned short*)(wsb + off); off += (size_t)EDGES*128*2;
    unsigned short* wH1m    = (unsigned short*)(wsb + off); off += (size_t)CH_EDGES*256*2;
    unsigned short* wH1e    = (unsigned short*)(wsb + off); off += (size_t)CH_EDGES*128*2;
    unsigned short* wPQw    = (unsigned short*)(wsb + off); off += (size_t)3*768*256*2;
    unsigned short* wEw     = (unsigned short*)(wsb + off); off += (size_t)3*384*128*2;
    unsigned short* wUe2w   = (unsigned short*)(wsb + off); off += (size_t)3*128*128*2;
    unsigned short* wM2w    = (unsigned short*)(wsb + off); off += (size_t)3*256*256*2;

    k_geom <<<16,    256, 0, stream>>>(X, C, wXc, wR, wF, out_maski);
    k_nodeh<<<NODES, 256, 0, stream>>>(wF, Wn, bn, C, out_node, wNodeBf);
    k_knn  <<<NODES/4, 256, 0, stream>>>(wXc, C, wEidx, out_eidxf);
    k_edge <<<NODES, 256, 0, stream>>>(wXc, wR, wEidx, C, We, be, wEdgeBf, out_maskij, wJg);

    k_pack_pqw<<<(3*768*256+255)/256, 256, 0, stream>>>(Wm1, Wue1, wPQw);
    k_pack_ew <<<(3*384*128+255)/256, 256, 0, stream>>>(Wm1, Wue1, wEw);
    k_pack_ue2<<<(3*128*128+255)/256, 256, 0, stream>>>(Wue2, wUe2w);
    k_pack_m2 <<<(3*256*256+255)/256, 256, 0, stream>>>(Wm2, wM2w);

    for (int l=0; l<3; ++l){
        k_pq<<<dim3(32,6), 256, 0, stream>>>(wNodeBf, wPQw + (size_t)l*768*256, wPQ);
        for (int ch=0; ch<NCHUNK; ++ch){
            int e0    = ch*CH_EDGES;
            int node0 = ch*CH_NODES;
            k_h1<<<dim3(CH_EDGES/128,3), 256, 0, stream>>>(
                wEdgeBf + (size_t)e0*128, wEw + (size_t)l*384*128, wPQ, wJg,
                bm1 + l*256, bue1 + l*128, wH1m, wH1e, e0);
            k_s<<<CH_NODES, 256, 0, stream>>>(wH1m, out_maskij, wS, wCnt, node0);
            k_node_gemm<<<dim3(CH_NODES/128,2), 256, 0, stream>>>(
                wS, wM2w + (size_t)l*256*256, bm2 + l*256, wCnt, out_maski,
                out_node, wNodeBf, node0);
            k_edge_upd<<<CH_EDGES/128, 256, 0, stream>>>(
                wH1e, wUe2w + (size_t)l*128*128, bue2 + l*128,
                out_maskij, wEdgeBf, out_edge,
                e0, (l==2) ? 1 : 0);
        }
    }
}

// Round 6
// 768.756 us; speedup vs baseline: 4.4051x; 1.2846x over previous
//
#include <hip/hip_runtime.h>
#include <math.h>

#define Bdim 2
#define Nn   2048
#define Kn   30
#define DNc  256
#define DEc  128
#define NODES (Bdim*Nn)      // 4096
#define EDGES (Bdim*Nn*Kn)   // 122880
#define EPSF 1e-6f

#define NCHUNK 2
#define CH_EDGES (EDGES/NCHUNK)   // 61440
#define CH_NODES (NODES/NCHUNK)   // 2048

#define BK 64
#define LDA (BK+8)    // padded GEMM LDS row (bf16 elems): 2-way on b128, ~free
#define LDP 136       // pqTile row stride (shorts): 272B rows -> 16B aligned, 4-bank stride

typedef __attribute__((ext_vector_type(8))) short short8;
typedef __attribute__((ext_vector_type(4))) float floatx4;

// fast softplus: v_exp_f32 + v_log_f32 (~7 instr); error ~1e-7 absolute, irrelevant at bf16
__device__ __forceinline__ float softplusf(float x){
    float e = __expf(-fabsf(x));
    return fmaxf(x, 0.f) + __logf(1.f + e);
}

__device__ __forceinline__ unsigned short f2bf(float x){
    union { float f; unsigned u; } v; v.f = x;
    unsigned r = v.u + 0x7fff + ((v.u >> 16) & 1);   // RNE
    return (unsigned short)(r >> 16);
}
__device__ __forceinline__ float bf2f(unsigned short h){
    union { unsigned u; float f; } v; v.u = ((unsigned)h) << 16;
    return v.f;
}

// ---------------- K1: per-node geometry ----------------
__global__ __launch_bounds__(256) void k_geom(
    const float* __restrict__ X, const int* __restrict__ C,
    float* __restrict__ Xc, float* __restrict__ Rm,
    float* __restrict__ feat, float* __restrict__ mask_out)
{
    int id = blockIdx.x*256 + threadIdx.x;
    if (id >= NODES) return;
    float a[4][3];
    #pragma unroll
    for (int t=0;t<4;++t)
        #pragma unroll
        for (int d=0;d<3;++d) a[t][d] = X[id*12 + t*3 + d];
    #pragma unroll
    for (int d=0; d<3; ++d){
        float s = __fadd_rn(__fadd_rn(__fadd_rn(a[0][d],a[1][d]),a[2][d]),a[3][d]);
        Xc[id*3+d] = __fmul_rn(s, 0.25f);
    }
    mask_out[id] = (C[id] > 0) ? 1.f : 0.f;

    float u[3], v[3], w[3], b2[3], v0[3], vv[3];
    #pragma unroll
    for (int d=0;d<3;++d) b2[d] = a[2][d]-a[1][d];
    float n2 = sqrtf(b2[0]*b2[0]+b2[1]*b2[1]+b2[2]*b2[2]);
    #pragma unroll
    for (int d=0;d<3;++d) u[d] = b2[d]/(n2+EPSF);
    #pragma unroll
    for (int d=0;d<3;++d) v0[d] = a[0][d]-a[1][d];
    float dt = v0[0]*u[0]+v0[1]*u[1]+v0[2]*u[2];
    #pragma unroll
    for (int d=0;d<3;++d) vv[d] = v0[d] - dt*u[d];
    float nv = sqrtf(vv[0]*vv[0]+vv[1]*vv[1]+vv[2]*vv[2]);
    #pragma unroll
    for (int d=0;d<3;++d) v[d] = vv[d]/(nv+EPSF);
    w[0] = u[1]*v[2]-u[2]*v[1];
    w[1] = u[2]*v[0]-u[0]*v[2];
    w[2] = u[0]*v[1]-u[1]*v[0];
    #pragma unroll
    for (int d=0;d<3;++d){
        Rm[id*9 + d*3 + 0] = u[d];
        Rm[id*9 + d*3 + 1] = v[d];
        Rm[id*9 + d*3 + 2] = w[d];
    }
    float bonds[3][3];
    #pragma unroll
    for (int d=0;d<3;++d){
        bonds[0][d] = a[1][d]-a[0][d];
        bonds[1][d] = b2[d];
        bonds[2][d] = a[3][d]-a[2][d];
    }
    #pragma unroll
    for (int bi=0;bi<3;++bi){
        float nb = sqrtf(bonds[bi][0]*bonds[bi][0]+bonds[bi][1]*bonds[bi][1]+bonds[bi][2]*bonds[bi][2]);
        #pragma unroll
        for (int d=0;d<3;++d) feat[id*12 + bi*4 + d] = bonds[bi][d]/(nb+EPSF);
        feat[id*12 + bi*4 + 3] = logf(nb+EPSF);
    }
}

// ---------------- K1b: node_h init (f32 + bf16) ----------------
__global__ __launch_bounds__(256) void k_nodeh(
    const float* __restrict__ feat, const float* __restrict__ Wn,
    const float* __restrict__ bn, const int* __restrict__ C,
    float* __restrict__ node_h, unsigned short* __restrict__ node_bf)
{
    int nid = blockIdx.x;
    int c   = threadIdx.x;
    __shared__ float f[12];
    if (c < 12) f[c] = feat[nid*12 + c];
    __syncthreads();
    float acc = bn[c];
    #pragma unroll
    for (int k=0;k<12;++k) acc += f[k]*Wn[k*DNc + c];
    float mask = (C[nid] > 0) ? 1.f : 0.f;
    float r = acc*mask;
    node_h[nid*DNc + c] = r;
    node_bf[nid*DNc + c] = f2bf(r);
}

// ---------------- K2: kNN top-30, wave-per-node, register selection ----------------
__global__ __launch_bounds__(256) void k_knn(
    const float* __restrict__ Xc, const int* __restrict__ C,
    int* __restrict__ eidx, float* __restrict__ eidx_f)
{
    __shared__ float sx[Nn], sy[Nn], sz[Nn], sadd[Nn];
    int tid  = threadIdx.x;
    int lane = tid & 63, wave = tid >> 6;
    int node0 = blockIdx.x*4;            // 4 nodes per block, same batch
    int base  = (node0 >> 11) << 11;     // batch base node
    for (int j=tid; j<Nn; j+=256){
        int gj = base + j;
        sx[j] = Xc[gj*3+0]; sy[j] = Xc[gj*3+1]; sz[j] = Xc[gj*3+2];
        sadd[j] = (C[gj] > 0) ? 0.f : 1e9f;
    }
    __syncthreads();

    int node = node0 + wave;
    int iloc = node & (Nn-1);
    float xi = sx[iloc], yi = sy[iloc], zi = sz[iloc];

    unsigned long long kreg[32];
    unsigned long long gm[8];
    #pragma unroll
    for (int t=0; t<32; ++t){
        int j = lane + t*64;
        float dx = __fsub_rn(xi, sx[j]);
        float dy = __fsub_rn(yi, sy[j]);
        float dz = __fsub_rn(zi, sz[j]);
        float vv = __fadd_rn(__fadd_rn(__fmul_rn(dx,dx),__fmul_rn(dy,dy)),__fmul_rn(dz,dz));
        vv = __fadd_rn(vv, sadd[j]);
        if (j == iloc) vv = __fadd_rn(vv, 1e9f);
        union { float f; unsigned u; } cv; cv.f = vv;
        kreg[t] = (((unsigned long long)cv.u) << 11) | (unsigned)j;
    }
    #pragma unroll
    for (int g=0; g<8; ++g){
        unsigned long long a = kreg[4*g+0], b = kreg[4*g+1];
        unsigned long long c = kreg[4*g+2], d = kreg[4*g+3];
        unsigned long long m1 = a<b?a:b, m2 = c<d?c:d;
        gm[g] = m1<m2?m1:m2;
    }
    unsigned long long m = gm[0]; int marg = 0;
    #pragma unroll
    for (int g=1; g<8; ++g) if (gm[g] < m){ m = gm[g]; marg = g; }

    for (int kk=0; kk<Kn; ++kk){
        unsigned long long best = m;
        #pragma unroll
        for (int d=1; d<64; d<<=1){
            unsigned long long o = __shfl_xor(best, d, 64);
            if (o < best) best = o;
        }
        if (lane == 0){
            int j = (int)(best & 2047ull);
            eidx  [(size_t)node*Kn + kk] = j;
            eidx_f[(size_t)node*Kn + kk] = (float)j;
        }
        if (m == best){
            #pragma unroll
            for (int g=0; g<8; ++g){
                if (marg == g){
                    #pragma unroll
                    for (int t=0; t<4; ++t)
                        if (kreg[4*g+t] == best) kreg[4*g+t] = ~0ull;
                    unsigned long long a = kreg[4*g+0], b = kreg[4*g+1];
                    unsigned long long c = kreg[4*g+2], d = kreg[4*g+3];
                    unsigned long long m1 = a<b?a:b, m2 = c<d?c:d;
                    gm[g] = m1<m2?m1:m2;
                }
            }
            m = gm[0]; marg = 0;
            #pragma unroll
            for (int g=1; g<8; ++g) if (gm[g] < m){ m = gm[g]; marg = g; }
        }
    }
}

// ---------------- K3: edge features -> bf16 edge_h0, mask_ij, eJg table ----------------
__global__ __launch_bounds__(256) void k_edge(
    const float* __restrict__ Xc, const float* __restrict__ Rm,
    const int* __restrict__ eidx, const int* __restrict__ C,
    const float* __restrict__ We, const float* __restrict__ be,
    unsigned short* __restrict__ edge_bf, float* __restrict__ mask_ij_out,
    int* __restrict__ eJg)
{
    __shared__ float sWe[28*128];
    __shared__ float sbe[128];
    __shared__ float sfeat[30][28];
    __shared__ float smij[30];
    __shared__ float sRi[9];
    int nid = blockIdx.x;
    int b   = nid >> 11;
    int tid = threadIdx.x;
    for (int idx=tid; idx<28*128; idx+=256) sWe[idx] = We[idx];
    if (tid < 128) sbe[tid] = be[tid];
    if (tid < 9)   sRi[tid] = Rm[nid*9 + tid];
    __syncthreads();
    if (tid < 30){
        int e  = nid*Kn + tid;
        int j  = eidx[e];
        int jb = (b<<11) + j;
        eJg[e] = jb;
        float d0 = Xc[jb*3+0]-Xc[nid*3+0];
        float d1 = Xc[jb*3+1]-Xc[nid*3+1];
        float d2v= Xc[jb*3+2]-Xc[nid*3+2];
        float dist = sqrtf(d0*d0+d1*d1+d2v*d2v);
        smij[tid] = (C[nid] > 0 && C[jb] > 0) ? 1.f : 0.f;
        #pragma unroll
        for (int c=0; c<16; ++c){
            float ctr = (20.f/15.f)*(float)c;
            float t = (dist - ctr)*(1.f/1.25f);
            sfeat[tid][c] = expf(-t*t);
        }
        #pragma unroll
        for (int cc=0; cc<3; ++cc){
            float loc = sRi[0*3+cc]*d0 + sRi[1*3+cc]*d1 + sRi[2*3+cc]*d2v;
            sfeat[tid][16+cc] = loc/(dist+EPSF);
        }
        float rj[9];
        #pragma unroll
        for (int q=0;q<9;++q) rj[q] = Rm[jb*9+q];
        #pragma unroll
        for (int ee=0; ee<3; ++ee)
            #pragma unroll
            for (int ff=0; ff<3; ++ff)
                sfeat[tid][19+ee*3+ff] = sRi[0+ee]*rj[0+ff] + sRi[3+ee]*rj[3+ff] + sRi[6+ee]*rj[6+ff];
        mask_ij_out[e] = smij[tid];
    }
    __syncthreads();
    int c  = tid & 127;
    int eg = tid >> 7;
    for (int e=eg; e<Kn; e+=2){
        float acc = sbe[c];
        #pragma unroll
        for (int f=0; f<28; ++f) acc += sfeat[e][f]*sWe[f*128 + c];
        edge_bf[(size_t)(nid*Kn + e)*DEc + c] = f2bf(acc * smij[e]);
    }
}

// ---------------- weight packing (bf16, B^T layouts) ----------------
__global__ __launch_bounds__(256) void k_pack_pqw(
    const float* __restrict__ Wm1, const float* __restrict__ Wue1,
    unsigned short* __restrict__ wPQw)
{
    int id = blockIdx.x*256 + threadIdx.x;
    if (id >= 3*768*256) return;
    int l = id / (768*256);
    int rem = id % (768*256);
    int n = rem >> 8, k = rem & 255;
    int c = (n < 384) ? n : n - 384;
    int r = (n < 384) ? k : 256 + k;
    float v = (c < 256) ? Wm1[((size_t)l*640 + r)*256 + c]
                        : Wue1[((size_t)l*640 + r)*128 + (c-256)];
    wPQw[id] = f2bf(v);
}

__global__ __launch_bounds__(256) void k_pack_ew(
    const float* __restrict__ Wm1, const float* __restrict__ Wue1,
    unsigned short* __restrict__ wEw)
{
    int id = blockIdx.x*256 + threadIdx.x;
    if (id >= 3*384*128) return;
    int l = id / (384*128);
    int rem = id % (384*128);
    int n = rem >> 7, k = rem & 127;
    int r = 512 + k;
    float v = (n < 256) ? Wm1[((size_t)l*640 + r)*256 + n]
                        : Wue1[((size_t)l*640 + r)*128 + (n-256)];
    wEw[id] = f2bf(v);
}

__global__ __launch_bounds__(256) void k_pack_ue2(
    const float* __restrict__ Wue2, unsigned short* __restrict__ wUe2w)
{
    int id = blockIdx.x*256 + threadIdx.x;
    if (id >= 3*128*128) return;
    int l = id / (128*128);
    int rem = id % (128*128);
    int n = rem >> 7, k = rem & 127;
    wUe2w[id] = f2bf(Wue2[((size_t)l*128 + k)*128 + n]);
}

__global__ __launch_bounds__(256) void k_pack_m2(
    const float* __restrict__ Wm2, unsigned short* __restrict__ wM2w)
{
    int id = blockIdx.x*256 + threadIdx.x;
    if (id >= 3*256*256) return;
    int l = id / (256*256);
    int rem = id % (256*256);
    int n = rem >> 8, k = rem & 255;
    wM2w[id] = f2bf(Wm2[((size_t)l*256 + k)*256 + n]);
}

// ---------------- MFMA GEMM helpers ----------------
__device__ __forceinline__ void stage_tile(
    const unsigned short* __restrict__ gbase, int ldg, int k0,
    unsigned short* lds, int tid)
{
    #pragma unroll
    for (int it=0; it<4; ++it){
        int idx = it*256 + tid;
        int row = idx >> 3;
        int ke  = (idx & 7) * 8;
        const float4* src = (const float4*)(gbase + (size_t)row*ldg + k0 + ke);
        *(float4*)(&lds[row*LDA + ke]) = *src;
    }
}

__device__ __forceinline__ void mma_tile(
    const unsigned short* Als, const unsigned short* Bls,
    int wm, int wn, int lane, floatx4 acc[4][4])
{
    #pragma unroll
    for (int s=0; s<2; ++s){
        short8 af[4], bf[4];
        int kidx = s*32 + (lane>>4)*8;
        #pragma unroll
        for (int t=0;t<4;++t){
            int row = wm*64 + t*16 + (lane&15);
            af[t] = *(const short8*)(&Als[row*LDA + kidx]);
            int col = wn*64 + t*16 + (lane&15);
            bf[t] = *(const short8*)(&Bls[col*LDA + kidx]);
        }
        #pragma unroll
        for (int i=0;i<4;++i)
            #pragma unroll
            for (int j=0;j<4;++j)
                acc[i][j] = __builtin_amdgcn_mfma_f32_16x16x32_bf16(af[i], bf[j], acc[i][j], 0,0,0);
    }
}

// ---------------- K-PQ: PQ(bf16) = node_bf @ wPQw^T, bias folded into P half ----------------
__global__ __launch_bounds__(256) void k_pq(
    const unsigned short* __restrict__ A, const unsigned short* __restrict__ Bw,
    unsigned short* __restrict__ PQbf,
    const float* __restrict__ bm1l, const float* __restrict__ bue1l)
{
    __shared__ __align__(16) unsigned short Als[128*LDA];
    __shared__ __align__(16) unsigned short Bls[128*LDA];
    int tid = threadIdx.x;
    int lane = tid & 63, wave = tid >> 6;
    int wm = wave >> 1, wn = wave & 1;
    const unsigned short* Ab = A + (size_t)blockIdx.x*128*256;
    const unsigned short* Bb = Bw + (size_t)blockIdx.y*128*256;
    floatx4 acc[4][4];
    #pragma unroll
    for (int i=0;i<4;++i)
        #pragma unroll
        for (int j=0;j<4;++j) acc[i][j] = (floatx4){0.f,0.f,0.f,0.f};
    for (int k0=0; k0<256; k0+=BK){
        stage_tile(Ab, 256, k0, Als, tid);
        stage_tile(Bb, 256, k0, Bls, tid);
        __syncthreads();
        mma_tile(Als, Bls, wm, wn, lane, acc);
        __syncthreads();
    }
    int quad = lane >> 4, cl = lane & 15;
    #pragma unroll
    for (int i=0;i<4;++i){
        #pragma unroll
        for (int rg=0;rg<4;++rg){
            int row = blockIdx.x*128 + wm*64 + i*16 + quad*4 + rg;
            #pragma unroll
            for (int j=0;j<4;++j){
                int col = blockIdx.y*128 + wn*64 + j*16 + cl;
                float biasv = 0.f;
                if (col < 256)       biasv = bm1l[col];
                else if (col < 384)  biasv = bue1l[col-256];
                PQbf[(size_t)row*768 + col] = f2bf(acc[i][j][rg] + biasv);
            }
        }
    }
}

// ---------------- K4: H1 = softplus(E + P[i] + Q[j]) — GEMM first, LDS reused for PQ ----------------
__global__ __launch_bounds__(256) void k_h1(
    const unsigned short* __restrict__ Aeh, const unsigned short* __restrict__ Bw,
    const unsigned short* __restrict__ PQbf, const int* __restrict__ eJg,
    unsigned short* __restrict__ H1m, unsigned short* __restrict__ H1e, int e0)
{
    // one LDS pool: GEMM uses [Als|Bls]; after GEMM the same memory becomes pqTile
    __shared__ __align__(16) unsigned short smem[2*128*LDA];   // 36864 B
    unsigned short* Als = smem;
    unsigned short* Bls = smem + 128*LDA;
    unsigned short* pqTile = smem;                              // 128*LDP = 34816 B <= pool

    int tid = threadIdx.x;
    int lane = tid & 63, wave = tid >> 6;
    int wm = wave >> 1, wn = wave & 1;
    int colblk = blockIdx.y;

    // ---- GEMM: E-tile @ W ----
    const unsigned short* Ab = Aeh + (size_t)blockIdx.x*128*128;
    const unsigned short* Bb = Bw + (size_t)colblk*128*128;
    floatx4 acc[4][4];
    #pragma unroll
    for (int i=0;i<4;++i)
        #pragma unroll
        for (int j=0;j<4;++j) acc[i][j] = (floatx4){0.f,0.f,0.f,0.f};
    for (int k0=0; k0<128; k0+=BK){
        stage_tile(Ab, 128, k0, Als, tid);
        stage_tile(Bb, 128, k0, Bls, tid);
        __syncthreads();
        mma_tile(Als, Bls, wm, wn, lane, acc);
        __syncthreads();
    }
    // Als/Bls dead from here; smem becomes pqTile.

    // ---- PQ gather -> pqTile (vectorized; bias already folded into P) ----
    {
        int rl = tid >> 1;
        int h  = tid & 1;
        int e  = e0 + blockIdx.x*128 + rl;
        int ni = e / Kn;
        int jg = eJg[e];
        int cb = colblk*128 + h*64;
        const unsigned short* Pr = PQbf + (size_t)ni*768 + cb;
        const unsigned short* Qr = PQbf + (size_t)jg*768 + 384 + cb;
        #pragma unroll
        for (int q=0; q<8; ++q){
            short8 pv = *(const short8*)(Pr + q*8);
            short8 qv = *(const short8*)(Qr + q*8);
            short8 ov;
            #pragma unroll
            for (int z=0; z<8; ++z)
                ov[z] = (short)f2bf(bf2f((unsigned short)pv[z]) + bf2f((unsigned short)qv[z]));
            *(short8*)(&pqTile[rl*LDP + h*64 + q*8]) = ov;
        }
    }
    __syncthreads();

    // ---- epilogue: softplus(acc + pq), in-place sole-owner overwrite ----
    int quad = lane >> 4, cl = lane & 15;
    #pragma unroll
    for (int i=0;i<4;++i){
        #pragma unroll
        for (int rg=0;rg<4;++rg){
            int rowl = wm*64 + i*16 + quad*4 + rg;
            #pragma unroll
            for (int j=0;j<4;++j){
                int coll = wn*64 + j*16 + cl;
                float pq = bf2f(pqTile[rowl*LDP + coll]);
                float v = softplusf(acc[i][j][rg] + pq);
                pqTile[rowl*LDP + coll] = f2bf(v);
            }
        }
    }
    __syncthreads();

    // ---- cooperative vector stores ----
    {
        int rl = tid >> 1;
        int h  = tid & 1;
        int rglob = blockIdx.x*128 + rl;   // chunk-local row
        if (colblk < 2){
            unsigned short* dst = H1m + (size_t)rglob*256 + colblk*128 + h*64;
            #pragma unroll
            for (int q=0; q<8; ++q)
                *(short8*)(dst + q*8) = *(const short8*)(&pqTile[rl*LDP + h*64 + q*8]);
        } else {
            unsigned short* dst = H1e + (size_t)rglob*128 + h*64;
            #pragma unroll
            for (int q=0; q<8; ++q)
                *(short8*)(dst + q*8) = *(const short8*)(&pqTile[rl*LDP + h*64 + q*8]);
        }
    }
}

// ---------------- K5a: S = sum_k mask*H1m, cnt ----------------
__global__ __launch_bounds__(256) void k_s(
    const unsigned short* __restrict__ H1m, const float* __restrict__ mask_ij,
    unsigned short* __restrict__ S, float* __restrict__ cnt, int node0)
{
    int ln = blockIdx.x;
    int c  = threadIdx.x;
    int nid = node0 + ln;
    const float* mij = mask_ij + (size_t)nid*Kn;
    float s = 0.f, ct = 0.f;
    #pragma unroll
    for (int k=0;k<Kn;++k){
        float mk = mij[k];
        ct += mk;
        s  += mk * bf2f(H1m[((size_t)ln*Kn + k)*256 + c]);
    }
    S[(size_t)ln*256 + c] = f2bf(s);
    if (c == 0) cnt[ln] = ct;
}

// ---------------- K5b: node_h = (node_h + (S@Wm2 + cnt*bm2)/denom)*mask ----------------
__global__ __launch_bounds__(256) void k_node_gemm(
    const unsigned short* __restrict__ S, const unsigned short* __restrict__ Bw,
    const float* __restrict__ bm2l, const float* __restrict__ cnt,
    const float* __restrict__ mask_i,
    float* __restrict__ node_h, unsigned short* __restrict__ node_bf, int node0)
{
    __shared__ __align__(16) unsigned short Als[128*LDA];
    __shared__ __align__(16) unsigned short Bls[128*LDA];
    int tid = threadIdx.x;
    int lane = tid & 63, wave = tid >> 6;
    int wm = wave >> 1, wn = wave & 1;
    const unsigned short* Ab = S + (size_t)blockIdx.x*128*256;
    const unsigned short* Bb = Bw + (size_t)blockIdx.y*128*256;
    floatx4 acc[4][4];
    #pragma unroll
    for (int i=0;i<4;++i)
        #pragma unroll
        for (int j=0;j<4;++j) acc[i][j] = (floatx4){0.f,0.f,0.f,0.f};
    for (int k0=0; k0<256; k0+=BK){
        stage_tile(Ab, 256, k0, Als, tid);
        stage_tile(Bb, 256, k0, Bls, tid);
        __syncthreads();
        mma_tile(Als, Bls, wm, wn, lane, acc);
        __syncthreads();
    }
    int quad = lane >> 4, cl = lane & 15;
    #pragma unroll
    for (int i=0;i<4;++i){
        #pragma unroll
        for (int rg=0;rg<4;++rg){
            int rl  = blockIdx.x*128 + wm*64 + i*16 + quad*4 + rg;
            int nid = node0 + rl;
            float ct = cnt[rl];
            float mi = mask_i[nid];
            #pragma unroll
            for (int j=0;j<4;++j){
                int col = blockIdx.y*128 + wn*64 + j*16 + cl;
                float msum = acc[i][j][rg] + ct*bm2l[col];
                float nh = node_h[(size_t)nid*256 + col];
                float r = (nh + msum/(ct+EPSF))*mi;
                node_h[(size_t)nid*256 + col] = r;
                node_bf[(size_t)nid*256 + col] = f2bf(r);
            }
        }
    }
}

// ---------------- K6: edge residual update (bf16 master, f32 out on last layer) ----------------
// NOTE: edge_bf / edge_f32 are UNOFFSET base pointers; indexing is global via e.
__global__ __launch_bounds__(256) void k_edge_upd(
    const unsigned short* __restrict__ H1e, const unsigned short* __restrict__ Bw,
    const float* __restrict__ bue2l, const float* __restrict__ mask_ij,
    unsigned short* __restrict__ edge_bf, float* __restrict__ edge_f32,
    int e0, int writeF32)
{
    __shared__ __align__(16) unsigned short Als[128*LDA];
    __shared__ __align__(16) unsigned short Bls[128*LDA];
    int tid = threadIdx.x;
    int lane = tid & 63, wave = tid >> 6;
    int wm = wave >> 1, wn = wave & 1;
    const unsigned short* Ab = H1e + (size_t)blockIdx.x*128*128;
    floatx4 acc[4][4];
    #pragma unroll
    for (int i=0;i<4;++i)
        #pragma unroll
        for (int j=0;j<4;++j) acc[i][j] = (floatx4){0.f,0.f,0.f,0.f};
    for (int k0=0; k0<128; k0+=BK){
        stage_tile(Ab, 128, k0, Als, tid);
        stage_tile(Bw, 128, k0, Bls, tid);
        __syncthreads();
        mma_tile(Als, Bls, wm, wn, lane, acc);
        __syncthreads();
    }
    int quad = lane >> 4, cl = lane & 15;
    #pragma unroll
    for (int i=0;i<4;++i){
        #pragma unroll
        for (int rg=0;rg<4;++rg){
            int rl = blockIdx.x*128 + wm*64 + i*16 + quad*4 + rg;
            int e  = e0 + rl;
            float mij = mask_ij[e];
            #pragma unroll
            for (int j=0;j<4;++j){
                int col = wn*64 + j*16 + cl;
                float old = bf2f(edge_bf[((size_t)e)*DEc + col]);
                float nv = (old + acc[i][j][rg] + bue2l[col]) * mij;
                edge_bf[((size_t)e)*DEc + col] = f2bf(nv);
                if (writeF32) edge_f32[((size_t)e)*DEc + col] = nv;
            }
        }
    }
}

extern "C" void kernel_launch(void* const* d_in, const int* in_sizes, int n_in,
                              void* d_out, int out_size, void* d_ws, size_t ws_size,
                              hipStream_t stream)
{
    (void)in_sizes; (void)n_in; (void)out_size; (void)ws_size;
    const float* X   = (const float*)d_in[0];
    const int*   C   = (const int*)  d_in[1];
    const float* Wn  = (const float*)d_in[2];
    const float* bn  = (const float*)d_in[3];
    const float* We  = (const float*)d_in[4];
    const float* be  = (const float*)d_in[5];
    const float* Wm1 = (const float*)d_in[6];
    const float* bm1 = (const float*)d_in[7];
    const float* Wm2 = (const float*)d_in[8];
    const float* bm2 = (const float*)d_in[9];
    const float* Wue1= (const float*)d_in[10];
    const float* bue1= (const float*)d_in[11];
    const float* Wue2= (const float*)d_in[12];
    const float* bue2= (const float*)d_in[13];

    float* out       = (float*)d_out;
    float* out_node  = out;                    // (B,N,DN)    1048576
    float* out_edge  = out + 1048576;          // (B,N,K,DE) 15728640
    float* out_eidxf = out + 16777216;         // (B,N,K)      122880
    float* out_maski = out + 16900096;         // (B,N)          4096
    float* out_maskij= out + 16904192;         // (B,N,K)      122880

    char* wsb = (char*)d_ws;
    size_t off = 0;
    float* wXc   = (float*)(wsb + off); off += (size_t)12288*4;
    float* wR    = (float*)(wsb + off); off += (size_t)36864*4;
    float* wF    = (float*)(wsb + off); off += (size_t)49152*4;
    int*   wEidx = (int*)  (wsb + off); off += (size_t)122880*4;
    int*   wJg   = (int*)  (wsb + off); off += (size_t)122880*4;
    float* wCnt  = (float*)(wsb + off); off += (size_t)CH_NODES*4;
    unsigned short* wPQ     = (unsigned short*)(wsb + off); off += (size_t)4096*768*2;
    unsigned short* wS      = (unsigned short*)(wsb + off); off += (size_t)CH_NODES*256*2;
    unsigned short* wNodeBf = (unsigned short*)(wsb + off); off += (size_t)4096*256*2;
    unsigned short* wEdgeBf = (unsigned short*)(wsb + off); off += (size_t)EDGES*128*2;
    unsigned short* wH1m    = (unsigned short*)(wsb + off); off += (size_t)CH_EDGES*256*2;
    unsigned short* wH1e    = (unsigned short*)(wsb + off); off += (size_t)CH_EDGES*128*2;
    unsigned short* wPQw    = (unsigned short*)(wsb + off); off += (size_t)3*768*256*2;
    unsigned short* wEw     = (unsigned short*)(wsb + off); off += (size_t)3*384*128*2;
    unsigned short* wUe2w   = (unsigned short*)(wsb + off); off += (size_t)3*128*128*2;
    unsigned short* wM2w    = (unsigned short*)(wsb + off); off += (size_t)3*256*256*2;

    k_geom <<<16,    256, 0, stream>>>(X, C, wXc, wR, wF, out_maski);
    k_nodeh<<<NODES, 256, 0, stream>>>(wF, Wn, bn, C, out_node, wNodeBf);
    k_knn  <<<NODES/4, 256, 0, stream>>>(wXc, C, wEidx, out_eidxf);
    k_edge <<<NODES, 256, 0, stream>>>(wXc, wR, wEidx, C, We, be, wEdgeBf, out_maskij, wJg);

    k_pack_pqw<<<(3*768*256+255)/256, 256, 0, stream>>>(Wm1, Wue1, wPQw);
    k_pack_ew <<<(3*384*128+255)/256, 256, 0, stream>>>(Wm1, Wue1, wEw);
    k_pack_ue2<<<(3*128*128+255)/256, 256, 0, stream>>>(Wue2, wUe2w);
    k_pack_m2 <<<(3*256*256+255)/256, 256, 0, stream>>>(Wm2, wM2w);

    for (int l=0; l<3; ++l){
        k_pq<<<dim3(32,6), 256, 0, stream>>>(wNodeBf, wPQw + (size_t)l*768*256, wPQ,
                                             bm1 + l*256, bue1 + l*128);
        for (int ch=0; ch<NCHUNK; ++ch){
            int e0    = ch*CH_EDGES;
            int node0 = ch*CH_NODES;
            k_h1<<<dim3(CH_EDGES/128,3), 256, 0, stream>>>(
                wEdgeBf + (size_t)e0*128, wEw + (size_t)l*384*128, wPQ, wJg,
                wH1m, wH1e, e0);
            k_s<<<CH_NODES, 256, 0, stream>>>(wH1m, out_maskij, wS, wCnt, node0);
            k_node_gemm<<<dim3(CH_NODES/128,2), 256, 0, stream>>>(
                wS, wM2w + (size_t)l*256*256, bm2 + l*256, wCnt, out_maski,
                out_node, wNodeBf, node0);
            k_edge_upd<<<CH_EDGES/128, 256, 0, stream>>>(
                wH1e, wUe2w + (size_t)l*128*128, bue2 + l*128,
                out_maskij, wEdgeBf, out_edge,
                e0, (l==2) ? 1 : 0);
        }
    }
}

// Round 7
// 683.206 us; speedup vs baseline: 4.9566x; 1.1252x over previous
//
#include <hip/hip_runtime.h>
#include <math.h>

#define Bdim 2
#define Nn   2048
#define Kn   30
#define KP   32                   // padded edges per node
#define DNc  256
#define DEc  128
#define NODES (Bdim*Nn)           // 4096
#define EDGES (Bdim*Nn*Kn)        // 122880
#define RPAD  (NODES*KP)          // 131072 padded edge rows
#define EPSF 1e-6f

#define BK 64
#define LDA (BK+8)    // padded GEMM LDS row (bf16 elems)
#define LDP 136       // LDS tile row stride (shorts), 16B-aligned rows

typedef __attribute__((ext_vector_type(8))) short short8;
typedef __attribute__((ext_vector_type(4))) float floatx4;

__device__ __forceinline__ float softplusf(float x){
    float e = __expf(-fabsf(x));
    return fmaxf(x, 0.f) + __logf(1.f + e);
}

__device__ __forceinline__ unsigned short f2bf(float x){
    union { float f; unsigned u; } v; v.f = x;
    unsigned r = v.u + 0x7fff + ((v.u >> 16) & 1);   // RNE
    return (unsigned short)(r >> 16);
}
__device__ __forceinline__ float bf2f(unsigned short h){
    union { unsigned u; float f; } v; v.u = ((unsigned)h) << 16;
    return v.f;
}

// ---------------- K1: per-node geometry ----------------
__global__ __launch_bounds__(256) void k_geom(
    const float* __restrict__ X, const int* __restrict__ C,
    float* __restrict__ Xc, float* __restrict__ Rm,
    float* __restrict__ feat, float* __restrict__ mask_out)
{
    int id = blockIdx.x*256 + threadIdx.x;
    if (id >= NODES) return;
    float a[4][3];
    #pragma unroll
    for (int t=0;t<4;++t)
        #pragma unroll
        for (int d=0;d<3;++d) a[t][d] = X[id*12 + t*3 + d];
    #pragma unroll
    for (int d=0; d<3; ++d){
        float s = __fadd_rn(__fadd_rn(__fadd_rn(a[0][d],a[1][d]),a[2][d]),a[3][d]);
        Xc[id*3+d] = __fmul_rn(s, 0.25f);
    }
    mask_out[id] = (C[id] > 0) ? 1.f : 0.f;

    float u[3], v[3], w[3], b2[3], v0[3], vv[3];
    #pragma unroll
    for (int d=0;d<3;++d) b2[d] = a[2][d]-a[1][d];
    float n2 = sqrtf(b2[0]*b2[0]+b2[1]*b2[1]+b2[2]*b2[2]);
    #pragma unroll
    for (int d=0;d<3;++d) u[d] = b2[d]/(n2+EPSF);
    #pragma unroll
    for (int d=0;d<3;++d) v0[d] = a[0][d]-a[1][d];
    float dt = v0[0]*u[0]+v0[1]*u[1]+v0[2]*u[2];
    #pragma unroll
    for (int d=0;d<3;++d) vv[d] = v0[d] - dt*u[d];
    float nv = sqrtf(vv[0]*vv[0]+vv[1]*vv[1]+vv[2]*vv[2]);
    #pragma unroll
    for (int d=0;d<3;++d) v[d] = vv[d]/(nv+EPSF);
    w[0] = u[1]*v[2]-u[2]*v[1];
    w[1] = u[2]*v[0]-u[0]*v[2];
    w[2] = u[0]*v[1]-u[1]*v[0];
    #pragma unroll
    for (int d=0;d<3;++d){
        Rm[id*9 + d*3 + 0] = u[d];
        Rm[id*9 + d*3 + 1] = v[d];
        Rm[id*9 + d*3 + 2] = w[d];
    }
    float bonds[3][3];
    #pragma unroll
    for (int d=0;d<3;++d){
        bonds[0][d] = a[1][d]-a[0][d];
        bonds[1][d] = b2[d];
        bonds[2][d] = a[3][d]-a[2][d];
    }
    #pragma unroll
    for (int bi=0;bi<3;++bi){
        float nb = sqrtf(bonds[bi][0]*bonds[bi][0]+bonds[bi][1]*bonds[bi][1]+bonds[bi][2]*bonds[bi][2]);
        #pragma unroll
        for (int d=0;d<3;++d) feat[id*12 + bi*4 + d] = bonds[bi][d]/(nb+EPSF);
        feat[id*12 + bi*4 + 3] = logf(nb+EPSF);
    }
}

// ---------------- K1b: node_h init (f32 + bf16) ----------------
__global__ __launch_bounds__(256) void k_nodeh(
    const float* __restrict__ feat, const float* __restrict__ Wn,
    const float* __restrict__ bn, const int* __restrict__ C,
    float* __restrict__ node_h, unsigned short* __restrict__ node_bf)
{
    int nid = blockIdx.x;
    int c   = threadIdx.x;
    __shared__ float f[12];
    if (c < 12) f[c] = feat[nid*12 + c];
    __syncthreads();
    float acc = bn[c];
    #pragma unroll
    for (int k=0;k<12;++k) acc += f[k]*Wn[k*DNc + c];
    float mask = (C[nid] > 0) ? 1.f : 0.f;
    float r = acc*mask;
    node_h[nid*DNc + c] = r;
    node_bf[nid*DNc + c] = f2bf(r);
}

// ---------------- K2: kNN top-30, wave-per-node, register selection ----------------
__global__ __launch_bounds__(256) void k_knn(
    const float* __restrict__ Xc, const int* __restrict__ C,
    int* __restrict__ eidx, float* __restrict__ eidx_f)
{
    __shared__ float sx[Nn], sy[Nn], sz[Nn], sadd[Nn];
    int tid  = threadIdx.x;
    int lane = tid & 63, wave = tid >> 6;
    int node0 = blockIdx.x*4;            // 4 nodes per block, same batch
    int base  = (node0 >> 11) << 11;     // batch base node
    for (int j=tid; j<Nn; j+=256){
        int gj = base + j;
        sx[j] = Xc[gj*3+0]; sy[j] = Xc[gj*3+1]; sz[j] = Xc[gj*3+2];
        sadd[j] = (C[gj] > 0) ? 0.f : 1e9f;
    }
    __syncthreads();

    int node = node0 + wave;
    int iloc = node & (Nn-1);
    float xi = sx[iloc], yi = sy[iloc], zi = sz[iloc];

    unsigned long long kreg[32];
    unsigned long long gm[8];
    #pragma unroll
    for (int t=0; t<32; ++t){
        int j = lane + t*64;
        float dx = __fsub_rn(xi, sx[j]);
        float dy = __fsub_rn(yi, sy[j]);
        float dz = __fsub_rn(zi, sz[j]);
        float vv = __fadd_rn(__fadd_rn(__fmul_rn(dx,dx),__fmul_rn(dy,dy)),__fmul_rn(dz,dz));
        vv = __fadd_rn(vv, sadd[j]);
        if (j == iloc) vv = __fadd_rn(vv, 1e9f);
        union { float f; unsigned u; } cv; cv.f = vv;
        kreg[t] = (((unsigned long long)cv.u) << 11) | (unsigned)j;
    }
    #pragma unroll
    for (int g=0; g<8; ++g){
        unsigned long long a = kreg[4*g+0], b = kreg[4*g+1];
        unsigned long long c = kreg[4*g+2], d = kreg[4*g+3];
        unsigned long long m1 = a<b?a:b, m2 = c<d?c:d;
        gm[g] = m1<m2?m1:m2;
    }
    unsigned long long m = gm[0]; int marg = 0;
    #pragma unroll
    for (int g=1; g<8; ++g) if (gm[g] < m){ m = gm[g]; marg = g; }

    for (int kk=0; kk<Kn; ++kk){
        unsigned long long best = m;
        #pragma unroll
        for (int d=1; d<64; d<<=1){
            unsigned long long o = __shfl_xor(best, d, 64);
            if (o < best) best = o;
        }
        if (lane == 0){
            int j = (int)(best & 2047ull);
            eidx  [(size_t)node*Kn + kk] = j;
            eidx_f[(size_t)node*Kn + kk] = (float)j;
        }
        if (m == best){
            #pragma unroll
            for (int g=0; g<8; ++g){
                if (marg == g){
                    #pragma unroll
                    for (int t=0; t<4; ++t)
                        if (kreg[4*g+t] == best) kreg[4*g+t] = ~0ull;
                    unsigned long long a = kreg[4*g+0], b = kreg[4*g+1];
                    unsigned long long c = kreg[4*g+2], d = kreg[4*g+3];
                    unsigned long long m1 = a<b?a:b, m2 = c<d?c:d;
                    gm[g] = m1<m2?m1:m2;
                }
            }
            m = gm[0]; marg = 0;
            #pragma unroll
            for (int g=1; g<8; ++g) if (gm[g] < m){ m = gm[g]; marg = g; }
        }
    }
}

// ---------------- K3: edge features -> PADDED bf16 edge_h0 + mask tables + cnt ----------------
__global__ __launch_bounds__(256) void k_edge(
    const float* __restrict__ Xc, const float* __restrict__ Rm,
    const int* __restrict__ eidx, const int* __restrict__ C,
    const float* __restrict__ We, const float* __restrict__ be,
    unsigned short* __restrict__ edge_pad, float* __restrict__ mask_ij_out,
    float* __restrict__ mask_pad, int* __restrict__ jg_pad,
    float* __restrict__ cnt)
{
    __shared__ float sWe[28*128];
    __shared__ float sbe[128];
    __shared__ float sfeat[30][28];
    __shared__ float smij[30];
    __shared__ float sRi[9];
    int nid = blockIdx.x;
    int b   = nid >> 11;
    int tid = threadIdx.x;
    for (int idx=tid; idx<28*128; idx+=256) sWe[idx] = We[idx];
    if (tid < 128) sbe[tid] = be[tid];
    if (tid < 9)   sRi[tid] = Rm[nid*9 + tid];
    __syncthreads();
    if (tid < KP){
        if (tid < Kn){
            int e  = nid*Kn + tid;
            int j  = eidx[e];
            int jb = (b<<11) + j;
            jg_pad[nid*KP + tid] = jb;
            float d0 = Xc[jb*3+0]-Xc[nid*3+0];
            float d1 = Xc[jb*3+1]-Xc[nid*3+1];
            float d2v= Xc[jb*3+2]-Xc[nid*3+2];
            float dist = sqrtf(d0*d0+d1*d1+d2v*d2v);
            float mij = (C[nid] > 0 && C[jb] > 0) ? 1.f : 0.f;
            smij[tid] = mij;
            mask_ij_out[e] = mij;
            mask_pad[nid*KP + tid] = mij;
            #pragma unroll
            for (int c=0; c<16; ++c){
                float ctr = (20.f/15.f)*(float)c;
                float t = (dist - ctr)*(1.f/1.25f);
                sfeat[tid][c] = expf(-t*t);
            }
            #pragma unroll
            for (int cc=0; cc<3; ++cc){
                float loc = sRi[0*3+cc]*d0 + sRi[1*3+cc]*d1 + sRi[2*3+cc]*d2v;
                sfeat[tid][16+cc] = loc/(dist+EPSF);
            }
            float rj[9];
            #pragma unroll
            for (int q=0;q<9;++q) rj[q] = Rm[jb*9+q];
            #pragma unroll
            for (int ee=0; ee<3; ++ee)
                #pragma unroll
                for (int ff=0; ff<3; ++ff)
                    sfeat[tid][19+ee*3+ff] = sRi[0+ee]*rj[0+ff] + sRi[3+ee]*rj[3+ff] + sRi[6+ee]*rj[6+ff];
        } else {
            jg_pad[nid*KP + tid] = nid;
            mask_pad[nid*KP + tid] = 0.f;
        }
    }
    __syncthreads();
    if (tid == 0){
        float c = 0.f;
        #pragma unroll
        for (int k=0;k<Kn;++k) c += smij[k];
        cnt[nid] = c;
    }
    int c  = tid & 127;
    int eg = tid >> 7;
    for (int k=eg; k<KP; k+=2){
        if (k < Kn){
            float acc = sbe[c];
            #pragma unroll
            for (int f=0; f<28; ++f) acc += sfeat[k][f]*sWe[f*128 + c];
            edge_pad[(size_t)(nid*KP + k)*DEc + c] = f2bf(acc * smij[k]);
        } else {
            edge_pad[(size_t)(nid*KP + k)*DEc + c] = 0;
        }
    }
}

// ---------------- weight packing (bf16, B^T layouts) ----------------
__global__ __launch_bounds__(256) void k_pack_pqw(
    const float* __restrict__ Wm1, const float* __restrict__ Wue1,
    unsigned short* __restrict__ wPQw)
{
    int id = blockIdx.x*256 + threadIdx.x;
    if (id >= 3*768*256) return;
    int l = id / (768*256);
    int rem = id % (768*256);
    int n = rem >> 8, k = rem & 255;
    int c = (n < 384) ? n : n - 384;
    int r = (n < 384) ? k : 256 + k;
    float v = (c < 256) ? Wm1[((size_t)l*640 + r)*256 + c]
                        : Wue1[((size_t)l*640 + r)*128 + (c-256)];
    wPQw[id] = f2bf(v);
}

__global__ __launch_bounds__(256) void k_pack_ew(
    const float* __restrict__ Wm1, const float* __restrict__ Wue1,
    unsigned short* __restrict__ wEw)
{
    int id = blockIdx.x*256 + threadIdx.x;
    if (id >= 3*384*128) return;
    int l = id / (384*128);
    int rem = id % (384*128);
    int n = rem >> 7, k = rem & 127;
    int r = 512 + k;
    float v = (n < 256) ? Wm1[((size_t)l*640 + r)*256 + n]
                        : Wue1[((size_t)l*640 + r)*128 + (n-256)];
    wEw[id] = f2bf(v);
}

__global__ __launch_bounds__(256) void k_pack_ue2(
    const float* __restrict__ Wue2, unsigned short* __restrict__ wUe2w)
{
    int id = blockIdx.x*256 + threadIdx.x;
    if (id >= 3*128*128) return;
    int l = id / (128*128);
    int rem = id % (128*128);
    int n = rem >> 7, k = rem & 127;
    wUe2w[id] = f2bf(Wue2[((size_t)l*128 + k)*128 + n]);
}

__global__ __launch_bounds__(256) void k_pack_m2(
    const float* __restrict__ Wm2, unsigned short* __restrict__ wM2w)
{
    int id = blockIdx.x*256 + threadIdx.x;
    if (id >= 3*256*256) return;
    int l = id / (256*256);
    int rem = id % (256*256);
    int n = rem >> 8, k = rem & 255;
    wM2w[id] = f2bf(Wm2[((size_t)l*256 + k)*256 + n]);
}

// ---------------- MFMA GEMM helpers ----------------
__device__ __forceinline__ void stage_tile(
    const unsigned short* __restrict__ gbase, int ldg, int k0,
    unsigned short* lds, int tid)
{
    #pragma unroll
    for (int it=0; it<4; ++it){
        int idx = it*256 + tid;
        int row = idx >> 3;
        int ke  = (idx & 7) * 8;
        const float4* src = (const float4*)(gbase + (size_t)row*ldg + k0 + ke);
        *(float4*)(&lds[row*LDA + ke]) = *src;
    }
}

__device__ __forceinline__ void mma_tile(
    const unsigned short* Als, const unsigned short* Bls,
    int wm, int wn, int lane, floatx4 acc[4][4])
{
    #pragma unroll
    for (int s=0; s<2; ++s){
        short8 af[4], bf[4];
        int kidx = s*32 + (lane>>4)*8;
        #pragma unroll
        for (int t=0;t<4;++t){
            int row = wm*64 + t*16 + (lane&15);
            af[t] = *(const short8*)(&Als[row*LDA + kidx]);
            int col = wn*64 + t*16 + (lane&15);
            bf[t] = *(const short8*)(&Bls[col*LDA + kidx]);
        }
        #pragma unroll
        for (int i=0;i<4;++i)
            #pragma unroll
            for (int j=0;j<4;++j)
                acc[i][j] = __builtin_amdgcn_mfma_f32_16x16x32_bf16(af[i], bf[j], acc[i][j], 0,0,0);
    }
}

// ---------------- K-PQ: PQ(bf16) = node_bf @ wPQw^T + bias, LDS-staged stores ----------------
__global__ __launch_bounds__(256) void k_pq(
    const unsigned short* __restrict__ A, const unsigned short* __restrict__ Bw,
    unsigned short* __restrict__ PQbf,
    const float* __restrict__ bm1l, const float* __restrict__ bue1l)
{
    __shared__ __align__(16) unsigned short smem[2*128*LDA];
    unsigned short* Als = smem;
    unsigned short* Bls = smem + 128*LDA;
    unsigned short* tile = smem;            // reuse after GEMM
    int tid = threadIdx.x;
    int lane = tid & 63, wave = tid >> 6;
    int wm = wave >> 1, wn = wave & 1;
    const unsigned short* Ab = A + (size_t)blockIdx.x*128*256;
    const unsigned short* Bb = Bw + (size_t)blockIdx.y*128*256;
    floatx4 acc[4][4];
    #pragma unroll
    for (int i=0;i<4;++i)
        #pragma unroll
        for (int j=0;j<4;++j) acc[i][j] = (floatx4){0.f,0.f,0.f,0.f};
    for (int k0=0; k0<256; k0+=BK){
        stage_tile(Ab, 256, k0, Als, tid);
        stage_tile(Bb, 256, k0, Bls, tid);
        __syncthreads();
        mma_tile(Als, Bls, wm, wn, lane, acc);
        __syncthreads();
    }
    int quad = lane >> 4, cl = lane & 15;
    #pragma unroll
    for (int i=0;i<4;++i){
        #pragma unroll
        for (int rg=0;rg<4;++rg){
            int rowl = wm*64 + i*16 + quad*4 + rg;
            #pragma unroll
            for (int j=0;j<4;++j){
                int coll = wn*64 + j*16 + cl;
                int col  = blockIdx.y*128 + coll;
                float biasv = 0.f;
                if (col < 256)       biasv = bm1l[col];
                else if (col < 384)  biasv = bue1l[col-256];
                tile[rowl*LDP + coll] = f2bf(acc[i][j][rg] + biasv);
            }
        }
    }
    __syncthreads();
    {
        int rl = tid >> 1;
        int h  = tid & 1;
        unsigned short* dst = PQbf + (size_t)(blockIdx.x*128 + rl)*768 + blockIdx.y*128 + h*64;
        #pragma unroll
        for (int q=0; q<8; ++q)
            *(short8*)(dst + q*8) = *(const short8*)(&tile[rl*LDP + h*64 + q*8]);
    }
}

// ---------------- K4: H1 = softplus(E + P[i] + Q[j]); fused masked node-sum -> S ----------------
// Padded rows: 128-row tile = exactly 4 nodes. colblk 0,1: write only S. colblk 2: write H1e_pad.
__global__ __launch_bounds__(256) void k_h1(
    const unsigned short* __restrict__ Apad, const unsigned short* __restrict__ Bw,
    const unsigned short* __restrict__ PQbf, const int* __restrict__ jg_pad,
    const float* __restrict__ mask_pad,
    unsigned short* __restrict__ Sout, unsigned short* __restrict__ H1e)
{
    __shared__ __align__(16) unsigned short smem[2*128*LDA];
    __shared__ float smask[128];
    unsigned short* Als = smem;
    unsigned short* Bls = smem + 128*LDA;
    unsigned short* pqTile = smem;

    int tid = threadIdx.x;
    int lane = tid & 63, wave = tid >> 6;
    int wm = wave >> 1, wn = wave & 1;
    int colblk = blockIdx.y;

    const unsigned short* Ab = Apad + (size_t)blockIdx.x*128*128;
    const unsigned short* Bb = Bw + (size_t)colblk*128*128;
    floatx4 acc[4][4];
    #pragma unroll
    for (int i=0;i<4;++i)
        #pragma unroll
        for (int j=0;j<4;++j) acc[i][j] = (floatx4){0.f,0.f,0.f,0.f};
    for (int k0=0; k0<128; k0+=BK){
        stage_tile(Ab, 128, k0, Als, tid);
        stage_tile(Bb, 128, k0, Bls, tid);
        __syncthreads();
        mma_tile(Als, Bls, wm, wn, lane, acc);
        __syncthreads();
    }

    // ---- PQ gather -> pqTile (padded row: node = r>>5, no division) ----
    {
        int rl = tid >> 1;
        int h  = tid & 1;
        int r  = blockIdx.x*128 + rl;
        int ni = r >> 5;
        int jg = jg_pad[r];
        int cb = colblk*128 + h*64;
        const unsigned short* Pr = PQbf + (size_t)ni*768 + cb;
        const unsigned short* Qr = PQbf + (size_t)jg*768 + 384 + cb;
        #pragma unroll
        for (int q=0; q<8; ++q){
            short8 pv = *(const short8*)(Pr + q*8);
            short8 qv = *(const short8*)(Qr + q*8);
            short8 ov;
            #pragma unroll
            for (int z=0; z<8; ++z)
                ov[z] = (short)f2bf(bf2f((unsigned short)pv[z]) + bf2f((unsigned short)qv[z]));
            *(short8*)(&pqTile[rl*LDP + h*64 + q*8]) = ov;
        }
        if (tid < 128) smask[tid] = mask_pad[blockIdx.x*128 + tid];
    }
    __syncthreads();

    int quad = lane >> 4, cl = lane & 15;
    float sumA[4] = {0.f,0.f,0.f,0.f};
    float sumB[4] = {0.f,0.f,0.f,0.f};
    #pragma unroll
    for (int i=0;i<4;++i){
        #pragma unroll
        for (int rg=0;rg<4;++rg){
            int rowl = wm*64 + i*16 + quad*4 + rg;
            float mk = smask[rowl];
            #pragma unroll
            for (int j=0;j<4;++j){
                int coll = wn*64 + j*16 + cl;
                float pq = bf2f(pqTile[rowl*LDP + coll]);
                float v = softplusf(acc[i][j][rg] + pq);
                if (colblk < 2){
                    float mv = mk*v;
                    if (i < 2) sumA[j] += mv; else sumB[j] += mv;
                } else {
                    pqTile[rowl*LDP + coll] = f2bf(v);   // sole-owner in-place
                }
            }
        }
    }

    if (colblk < 2){
        // rows wm*64..wm*64+63 = nodes (bx*4 + 2wm), (bx*4 + 2wm + 1)
        int nodeA = blockIdx.x*4 + wm*2;
        #pragma unroll
        for (int j=0;j<4;++j){
            float a = sumA[j];
            a += __shfl_xor(a, 16, 64);
            a += __shfl_xor(a, 32, 64);
            float b = sumB[j];
            b += __shfl_xor(b, 16, 64);
            b += __shfl_xor(b, 32, 64);
            int col = colblk*128 + wn*64 + j*16 + cl;
            if (quad == 0)      Sout[(size_t)nodeA*256 + col]     = f2bf(a);
            else if (quad == 1) Sout[(size_t)(nodeA+1)*256 + col] = f2bf(b);
        }
    } else {
        __syncthreads();
        int rl = tid >> 1;
        int h  = tid & 1;
        int r  = blockIdx.x*128 + rl;
        unsigned short* dst = H1e + (size_t)r*128 + h*64;
        #pragma unroll
        for (int q=0; q<8; ++q)
            *(short8*)(dst + q*8) = *(const short8*)(&pqTile[rl*LDP + h*64 + q*8]);
    }
}

// ---------------- K5: node_h = (node_h + (S@Wm2 + cnt*bm2)/denom)*mask ----------------
__global__ __launch_bounds__(256) void k_node_gemm(
    const unsigned short* __restrict__ S, const unsigned short* __restrict__ Bw,
    const float* __restrict__ bm2l, const float* __restrict__ cnt,
    const float* __restrict__ mask_i,
    float* __restrict__ node_h, unsigned short* __restrict__ node_bf)
{
    __shared__ __align__(16) unsigned short Als[128*LDA];
    __shared__ __align__(16) unsigned short Bls[128*LDA];
    int tid = threadIdx.x;
    int lane = tid & 63, wave = tid >> 6;
    int wm = wave >> 1, wn = wave & 1;
    const unsigned short* Ab = S + (size_t)blockIdx.x*128*256;
    const unsigned short* Bb = Bw + (size_t)blockIdx.y*128*256;
    floatx4 acc[4][4];
    #pragma unroll
    for (int i=0;i<4;++i)
        #pragma unroll
        for (int j=0;j<4;++j) acc[i][j] = (floatx4){0.f,0.f,0.f,0.f};
    for (int k0=0; k0<256; k0+=BK){
        stage_tile(Ab, 256, k0, Als, tid);
        stage_tile(Bb, 256, k0, Bls, tid);
        __syncthreads();
        mma_tile(Als, Bls, wm, wn, lane, acc);
        __syncthreads();
    }
    int quad = lane >> 4, cl = lane & 15;
    #pragma unroll
    for (int i=0;i<4;++i){
        #pragma unroll
        for (int rg=0;rg<4;++rg){
            int nid = blockIdx.x*128 + wm*64 + i*16 + quad*4 + rg;
            float ct = cnt[nid];
            float mi = mask_i[nid];
            #pragma unroll
            for (int j=0;j<4;++j){
                int col = blockIdx.y*128 + wn*64 + j*16 + cl;
                float msum = acc[i][j][rg] + ct*bm2l[col];
                float nh = node_h[(size_t)nid*256 + col];
                float r = (nh + msum/(ct+EPSF))*mi;
                node_h[(size_t)nid*256 + col] = r;
                node_bf[(size_t)nid*256 + col] = f2bf(r);
            }
        }
    }
}

// ---------------- K6: edge residual update (padded master), LDS-staged epilogue ----------------
__global__ __launch_bounds__(256) void k_edge_upd(
    const unsigned short* __restrict__ H1e, const unsigned short* __restrict__ Bw,
    const float* __restrict__ bue2l, const float* __restrict__ mask_pad,
    unsigned short* __restrict__ edge_pad, float* __restrict__ edge_f32,
    int writeF32)
{
    __shared__ __align__(16) unsigned short smem[2*128*LDA];
    __shared__ float sbias[128];
    unsigned short* Als = smem;
    unsigned short* Bls = smem + 128*LDA;
    unsigned short* tile = smem;
    int tid = threadIdx.x;
    int lane = tid & 63, wave = tid >> 6;
    int wm = wave >> 1, wn = wave & 1;
    if (tid < 128) sbias[tid] = bue2l[tid];
    const unsigned short* Ab = H1e + (size_t)blockIdx.x*128*128;
    floatx4 acc[4][4];
    #pragma unroll
    for (int i=0;i<4;++i)
        #pragma unroll
        for (int j=0;j<4;++j) acc[i][j] = (floatx4){0.f,0.f,0.f,0.f};
    for (int k0=0; k0<128; k0+=BK){
        stage_tile(Ab, 128, k0, Als, tid);
        stage_tile(Bw, 128, k0, Bls, tid);
        __syncthreads();
        mma_tile(Als, Bls, wm, wn, lane, acc);
        __syncthreads();
    }
    int quad = lane >> 4, cl = lane & 15;
    #pragma unroll
    for (int i=0;i<4;++i){
        #pragma unroll
        for (int rg=0;rg<4;++rg){
            int rowl = wm*64 + i*16 + quad*4 + rg;
            #pragma unroll
            for (int j=0;j<4;++j){
                int coll = wn*64 + j*16 + cl;
                tile[rowl*LDP + coll] = f2bf(acc[i][j][rg]);
            }
        }
    }
    __syncthreads();
    {
        int rl = tid >> 1;
        int h  = tid & 1;
        int r  = blockIdx.x*128 + rl;
        int k  = r & (KP-1);
        if (k < Kn){
            float mij = mask_pad[r];
            int node = r >> 5;
            int e = node*Kn + k;
            unsigned short* ep = edge_pad + (size_t)r*128 + h*64;
            float* fp = edge_f32 + (size_t)e*128 + h*64;
            #pragma unroll
            for (int q=0; q<8; ++q){
                short8 ov = *(const short8*)(ep + q*8);
                short8 av = *(const short8*)(&tile[rl*LDP + h*64 + q*8]);
                float4 b0 = *(const float4*)(&sbias[h*64 + q*8]);
                float4 b1 = *(const float4*)(&sbias[h*64 + q*8 + 4]);
                float nv[8];
                nv[0] = (bf2f((unsigned short)ov[0]) + bf2f((unsigned short)av[0]) + b0.x)*mij;
                nv[1] = (bf2f((unsigned short)ov[1]) + bf2f((unsigned short)av[1]) + b0.y)*mij;
                nv[2] = (bf2f((unsigned short)ov[2]) + bf2f((unsigned short)av[2]) + b0.z)*mij;
                nv[3] = (bf2f((unsigned short)ov[3]) + bf2f((unsigned short)av[3]) + b0.w)*mij;
                nv[4] = (bf2f((unsigned short)ov[4]) + bf2f((unsigned short)av[4]) + b1.x)*mij;
                nv[5] = (bf2f((unsigned short)ov[5]) + bf2f((unsigned short)av[5]) + b1.y)*mij;
                nv[6] = (bf2f((unsigned short)ov[6]) + bf2f((unsigned short)av[6]) + b1.z)*mij;
                nv[7] = (bf2f((unsigned short)ov[7]) + bf2f((unsigned short)av[7]) + b1.w)*mij;
                short8 sv;
                #pragma unroll
                for (int z=0; z<8; ++z) sv[z] = (short)f2bf(nv[z]);
                *(short8*)(ep + q*8) = sv;
                if (writeF32){
                    float4 f0 = {nv[0],nv[1],nv[2],nv[3]};
                    float4 f1 = {nv[4],nv[5],nv[6],nv[7]};
                    *(float4*)(fp + q*8)     = f0;
                    *(float4*)(fp + q*8 + 4) = f1;
                }
            }
        }
    }
}

extern "C" void kernel_launch(void* const* d_in, const int* in_sizes, int n_in,
                              void* d_out, int out_size, void* d_ws, size_t ws_size,
                              hipStream_t stream)
{
    (void)in_sizes; (void)n_in; (void)out_size; (void)ws_size;
    const float* X   = (const float*)d_in[0];
    const int*   C   = (const int*)  d_in[1];
    const float* Wn  = (const float*)d_in[2];
    const float* bn  = (const float*)d_in[3];
    const float* We  = (const float*)d_in[4];
    const float* be  = (const float*)d_in[5];
    const float* Wm1 = (const float*)d_in[6];
    const float* bm1 = (const float*)d_in[7];
    const float* Wm2 = (const float*)d_in[8];
    const float* bm2 = (const float*)d_in[9];
    const float* Wue1= (const float*)d_in[10];
    const float* bue1= (const float*)d_in[11];
    const float* Wue2= (const float*)d_in[12];
    const float* bue2= (const float*)d_in[13];

    float* out       = (float*)d_out;
    float* out_node  = out;                    // (B,N,DN)    1048576
    float* out_edge  = out + 1048576;          // (B,N,K,DE) 15728640
    float* out_eidxf = out + 16777216;         // (B,N,K)      122880
    float* out_maski = out + 16900096;         // (B,N)          4096
    float* out_maskij= out + 16904192;         // (B,N,K)      122880

    char* wsb = (char*)d_ws;
    size_t off = 0;
    float* wXc    = (float*)(wsb + off); off += (size_t)12288*4;
    float* wR     = (float*)(wsb + off); off += (size_t)36864*4;
    float* wF     = (float*)(wsb + off); off += (size_t)49152*4;
    int*   wEidx  = (int*)  (wsb + off); off += (size_t)EDGES*4;
    int*   wJgPad = (int*)  (wsb + off); off += (size_t)RPAD*4;
    float* wMaskP = (float*)(wsb + off); off += (size_t)RPAD*4;
    float* wCnt   = (float*)(wsb + off); off += (size_t)NODES*4;
    unsigned short* wPQ      = (unsigned short*)(wsb + off); off += (size_t)NODES*768*2;
    unsigned short* wS       = (unsigned short*)(wsb + off); off += (size_t)NODES*256*2;
    unsigned short* wNodeBf  = (unsigned short*)(wsb + off); off += (size_t)NODES*256*2;
    unsigned short* wEdgePad = (unsigned short*)(wsb + off); off += (size_t)RPAD*128*2;
    unsigned short* wH1ePad  = (unsigned short*)(wsb + off); off += (size_t)RPAD*128*2;
    unsigned short* wPQw     = (unsigned short*)(wsb + off); off += (size_t)3*768*256*2;
    unsigned short* wEw      = (unsigned short*)(wsb + off); off += (size_t)3*384*128*2;
    unsigned short* wUe2w    = (unsigned short*)(wsb + off); off += (size_t)3*128*128*2;
    unsigned short* wM2w     = (unsigned short*)(wsb + off); off += (size_t)3*256*256*2;

    k_geom <<<16,    256, 0, stream>>>(X, C, wXc, wR, wF, out_maski);
    k_nodeh<<<NODES, 256, 0, stream>>>(wF, Wn, bn, C, out_node, wNodeBf);
    k_knn  <<<NODES/4, 256, 0, stream>>>(wXc, C, wEidx, out_eidxf);
    k_edge <<<NODES, 256, 0, stream>>>(wXc, wR, wEidx, C, We, be,
                                       wEdgePad, out_maskij, wMaskP, wJgPad, wCnt);

    k_pack_pqw<<<(3*768*256+255)/256, 256, 0, stream>>>(Wm1, Wue1, wPQw);
    k_pack_ew <<<(3*384*128+255)/256, 256, 0, stream>>>(Wm1, Wue1, wEw);
    k_pack_ue2<<<(3*128*128+255)/256, 256, 0, stream>>>(Wue2, wUe2w);
    k_pack_m2 <<<(3*256*256+255)/256, 256, 0, stream>>>(Wm2, wM2w);

    for (int l=0; l<3; ++l){
        k_pq<<<dim3(32,6), 256, 0, stream>>>(wNodeBf, wPQw + (size_t)l*768*256, wPQ,
                                             bm1 + l*256, bue1 + l*128);
        k_h1<<<dim3(RPAD/128,3), 256, 0, stream>>>(
            wEdgePad, wEw + (size_t)l*384*128, wPQ, wJgPad, wMaskP,
            wS, wH1ePad);
        k_node_gemm<<<dim3(NODES/128,2), 256, 0, stream>>>(
            wS, wM2w + (size_t)l*256*256, bm2 + l*256, wCnt, out_maski,
            out_node, wNodeBf);
        k_edge_upd<<<RPAD/128, 256, 0, stream>>>(
            wH1ePad, wUe2w + (size_t)l*128*128, bue2 + l*128,
            wMaskP, wEdgePad, out_edge, (l==2) ? 1 : 0);
    }
}